// Round 1
// 322.947 us; speedup vs baseline: 1.0693x; 1.0693x over previous
//
#include <hip/hip_runtime.h>
#include <math.h>

#define N_NODES 50000
#define N_EDGES 800000
#define F_IN    512
#define H1      8
#define F_HID   8
#define C1      64      // H1*F_HID
#define NLAB    64
#define SLOPE   0.2f

#define NBLK_SCAN 196   // ceil(50000/256)
#define NBLK_HIST 782   // ceil(800000/4/256)
#define NBLK_WT   128   // 64*512/256
#define NBLK_G1   782   // (50000+63)/64 gemm1 row-blocks (also = scatter blocks)
#define REC1     160    // [es1: 8 f32 | Wh1: 64 bf16] (2 cache lines)
#define REC2     144    // [es2: f32, pad | Wh2: 64 bf16]

typedef __attribute__((ext_vector_type(8))) short short8;
typedef __attribute__((ext_vector_type(4))) float f32x4;

__device__ __forceinline__ float bf_lo(unsigned u) { return __uint_as_float(u << 16); }
__device__ __forceinline__ float bf_hi(unsigned u) { return __uint_as_float(u & 0xFFFF0000u); }
__device__ __forceinline__ unsigned short f2bf(float x) {
    unsigned bits = __float_as_uint(x);
    return (unsigned short)((bits + 0x7FFF + ((bits >> 16) & 1)) >> 16);   // RNE
}

// ---------------- fused: edge histogram (blocks 0..781) + W1 split (782..909) ----------
__global__ void k_histwt(const int* __restrict__ dst, int* __restrict__ deg,
                         const float* __restrict__ W1, unsigned short* __restrict__ Bh,
                         unsigned short* __restrict__ Bl) {
    int b = blockIdx.x;
    if (b < NBLK_HIST) {
        int e4 = (b * 256 + threadIdx.x) * 4;
        if (e4 >= N_EDGES) return;
        int4 d4 = *(const int4*)(dst + e4);
        atomicAdd(&deg[d4.x], 1);
        atomicAdd(&deg[d4.y], 1);
        atomicAdd(&deg[d4.z], 1);
        atomicAdd(&deg[d4.w], 1);
    } else {
        int i = (b - NBLK_HIST) * 256 + threadIdx.x;   // 0..32767
        int c = i >> 9, f = i & 511;
        float v = W1[(c >> 3) * (F_IN * F_HID) + f * F_HID + (c & 7)];
        unsigned bits = __float_as_uint(v);
        float r = v - __uint_as_float(bits & 0xFFFF0000u);
        Bh[i] = (unsigned short)(bits >> 16);
        Bl[i] = (unsigned short)(__float_as_uint(r) >> 16);
    }
}

__global__ void k_scan1(const int* __restrict__ deg, int* __restrict__ rowptr,
                        int* __restrict__ bsums) {
    __shared__ int s[256];
    int t = threadIdx.x;
    int g = blockIdx.x * 256 + t;
    int v = (g < N_NODES) ? deg[g] : 0;
    s[t] = v;
    __syncthreads();
    #pragma unroll
    for (int off = 1; off < 256; off <<= 1) {
        int a = s[t];
        int b = (t >= off) ? s[t - off] : 0;
        __syncthreads();
        s[t] = a + b;
        __syncthreads();
    }
    if (g < N_NODES) rowptr[g] = s[t] - v;
    if (t == 255) bsums[blockIdx.x] = s[t];
}

__global__ void k_scan23(const int* __restrict__ bsums, int* __restrict__ rowptr) {
    __shared__ int s[256];
    int t = threadIdx.x;
    s[t] = (t < NBLK_SCAN) ? bsums[t] : 0;
    __syncthreads();
    #pragma unroll
    for (int off = 1; off < 256; off <<= 1) {
        int a = s[t];
        int b = (t >= off) ? s[t - off] : 0;
        __syncthreads();
        s[t] = a + b;
        __syncthreads();
    }
    int boff = (blockIdx.x == 0) ? 0 : s[blockIdx.x - 1];
    int g = blockIdx.x * 256 + t;
    if (g < N_NODES) rowptr[g] += boff;
}

// ---------------- GEMM1 + es/ed/record pack, FUSED with CSR scatter ----------
// Grid = 2*NBLK_G1. Odd blocks: edge scatter (latency-bound atomics, hidden under
// the even blocks' MFMA/VALU work). Even blocks: the R8 GEMM1 path, row block
// = blockIdx.x>>1. Scatter post-increments rowptr (ends at start+deg; consumers
// subtract deg).
__launch_bounds__(256)
__global__ void k_gemm1p(const float* __restrict__ X, const unsigned short* __restrict__ Bh,
                         const unsigned short* __restrict__ Bl, const float* __restrict__ a_s,
                         const float* __restrict__ a_d, char* __restrict__ rec,
                         float* __restrict__ ed,
                         const int* __restrict__ src, const int* __restrict__ dst,
                         int* __restrict__ rowptr, int* __restrict__ col) {
    __shared__ unsigned short sBh[64][136];
    __shared__ unsigned short sBl[64][136];

    if (blockIdx.x & 1) {          // ---- scatter path (block-uniform branch) ----
        int e4 = ((blockIdx.x >> 1) * 256 + threadIdx.x) * 4;
        if (e4 >= N_EDGES) return;
        int4 s4 = *(const int4*)(src + e4);
        int4 d4 = *(const int4*)(dst + e4);
        col[atomicAdd(&rowptr[d4.x], 1)] = s4.x;
        col[atomicAdd(&rowptr[d4.y], 1)] = s4.y;
        col[atomicAdd(&rowptr[d4.z], 1)] = s4.z;
        col[atomicAdd(&rowptr[d4.w], 1)] = s4.w;
        return;
    }

    const int t = threadIdx.x;
    const int lane = t & 63, w = t >> 6;
    const int r0 = (blockIdx.x >> 1) * 64 + w * 16;
    const int m = lane & 15, quad = lane >> 4;
    int row = r0 + m; if (row >= N_NODES) row = N_NODES - 1;
    const float* xrow = X + (size_t)row * F_IN + quad * 8;

    const int sc = t >> 2;
    const int sp = t & 3;

    f32x4 acc[4] = {};
    float4 pxa[4], pxb[4];
    #pragma unroll
    for (int i = 0; i < 4; i++) {
        pxa[i] = *(const float4*)(xrow + i * 32);
        pxb[i] = *(const float4*)(xrow + i * 32 + 4);
    }

    for (int chunk = 0; chunk < 4; chunk++) {
        const int k0 = chunk * 128;
        if (chunk) __syncthreads();
        #pragma unroll
        for (int i = 0; i < 4; i++) {
            *(short8*)(&sBh[sc][sp * 32 + i * 8]) =
                *(const short8*)(Bh + sc * F_IN + k0 + sp * 32 + i * 8);
            *(short8*)(&sBl[sc][sp * 32 + i * 8]) =
                *(const short8*)(Bl + sc * F_IN + k0 + sp * 32 + i * 8);
        }
        __syncthreads();
        #pragma unroll
        for (int i = 0; i < 4; i++) {
            float xs[8] = {pxa[i].x, pxa[i].y, pxa[i].z, pxa[i].w,
                           pxb[i].x, pxb[i].y, pxb[i].z, pxb[i].w};
            if (chunk < 3) {
                const int ktn = k0 + 128 + i * 32;
                pxa[i] = *(const float4*)(xrow + ktn);
                pxb[i] = *(const float4*)(xrow + ktn + 4);
            }
            short8 ah, al;
            #pragma unroll
            for (int j = 0; j < 8; j++) {
                unsigned bits = __float_as_uint(xs[j]);
                float r = xs[j] - __uint_as_float(bits & 0xFFFF0000u);
                ah[j] = (short)(bits >> 16);
                al[j] = (short)(__float_as_uint(r) >> 16);
            }
            #pragma unroll
            for (int s = 0; s < 4; s++) {
                short8 bh = *(const short8*)(&sBh[s * 16 + m][i * 32 + quad * 8]);
                short8 bl = *(const short8*)(&sBl[s * 16 + m][i * 32 + quad * 8]);
                acc[s] = __builtin_amdgcn_mfma_f32_16x16x32_bf16(al, bh, acc[s], 0, 0, 0);
                acc[s] = __builtin_amdgcn_mfma_f32_16x16x32_bf16(ah, bl, acc[s], 0, 0, 0);
                acc[s] = __builtin_amdgcn_mfma_f32_16x16x32_bf16(ah, bh, acc[s], 0, 0, 0);
            }
        }
    }
    __syncthreads();
    unsigned short* sWh = &sBh[0][0] + w * 1024;
    #pragma unroll
    for (int s = 0; s < 4; s++)
        #pragma unroll
        for (int reg = 0; reg < 4; reg++)
            sWh[(quad * 4 + reg) * 64 + s * 16 + m] = f2bf(acc[s][reg]);
    __syncthreads();
    const int rr = lane & 15, p = lane >> 4;
    const int n = r0 + rr;
    if (n >= N_NODES) return;
    float es2v[2], edv[2];
    #pragma unroll
    for (int hh = 0; hh < 2; hh++) {
        int h = 2 * p + hh;
        float s = 0.f, dsum = 0.f;
        #pragma unroll
        for (int j = 0; j < 8; j++) {
            float v = __uint_as_float((unsigned)sWh[rr * 64 + h * 8 + j] << 16);
            s += v * a_s[h * 8 + j];
            dsum += v * a_d[h * 8 + j];
        }
        es2v[hh] = s; edv[hh] = dsum;
    }
    char* r = rec + (size_t)n * REC1;
    *(float2*)(r + p * 8) = make_float2(es2v[0], es2v[1]);
    *(short8*)(r + 32 + p * 32)      = *(const short8*)(sWh + rr * 64 + p * 16);
    *(short8*)(r + 32 + p * 32 + 16) = *(const short8*)(sWh + rr * 64 + p * 16 + 8);
    *(float2*)(ed + n * 8 + 2 * p) = make_float2(edv[0], edv[1]);
}

// ---------------- layer-1 aggregation: GROUP-PER-NODE (8 lanes/node) ----------------
// lane q of each 8-lane group owns head q (= channels 8q..8q+7). No cross-group
// reduction: den and acc are lane-private. 2x edge unroll for ILP.
__launch_bounds__(256)
__global__ void k_agg1(const char* __restrict__ rec, const float* __restrict__ ed,
                       const int* __restrict__ rowptr, const int* __restrict__ deg,
                       const int* __restrict__ col, float* __restrict__ h2) {
    int tid = blockIdx.x * 256 + threadIdx.x;
    int n = tid >> 3, q = tid & 7;
    if (n >= N_NODES) return;
    int d = deg[n];
    int start = rowptr[n] - d;
    float edq = ed[n * 8 + q];

    float den = 0.f;
    float acc[8] = {};
    for (int e = 0; e < d; e += 2) {
        int sv0 = col[start + e];
        int sv1 = col[start + min(e + 1, d - 1)];
        const char* r0 = rec + (size_t)sv0 * REC1;
        const char* r1 = rec + (size_t)sv1 * REC1;
        float x0 = *(const float*)(r0 + q * 4) + edq;
        float x1 = *(const float*)(r1 + q * 4) + edq;
        uint4 u0 = *(const uint4*)(r0 + 32 + q * 16);
        uint4 u1 = *(const uint4*)(r1 + 32 + q * 16);
        x0 = x0 > 0.f ? x0 : SLOPE * x0;
        x1 = x1 > 0.f ? x1 : SLOPE * x1;
        float w0 = __expf(x0);
        float w1 = (e + 1 < d) ? __expf(x1) : 0.f;
        den += w0 + w1;
        float f0[8] = {bf_lo(u0.x), bf_hi(u0.x), bf_lo(u0.y), bf_hi(u0.y),
                       bf_lo(u0.z), bf_hi(u0.z), bf_lo(u0.w), bf_hi(u0.w)};
        float f1[8] = {bf_lo(u1.x), bf_hi(u1.x), bf_lo(u1.y), bf_hi(u1.y),
                       bf_lo(u1.z), bf_hi(u1.z), bf_lo(u1.w), bf_hi(u1.w)};
        #pragma unroll
        for (int j = 0; j < 8; j++) acc[j] += w0 * f0[j] + w1 * f1[j];
    }
    float inv = 1.f / (den + 1e-10f);
    float o[8];
    #pragma unroll
    for (int j = 0; j < 8; j++) {
        float v = acc[j] * inv;
        o[j] = v > 0.f ? v : expm1f(v);   // fused ELU
    }
    float4* hp = (float4*)(h2 + (size_t)n * 64 + q * 8);
    hp[0] = make_float4(o[0], o[1], o[2], o[3]);
    hp[1] = make_float4(o[4], o[5], o[6], o[7]);
}

// ---------------- GEMM2 (K=64), 16 nodes/block; writes record2 + ed2 ----------------
__launch_bounds__(256)
__global__ void k_gemm2(const float* __restrict__ h2, const float* __restrict__ W2,
                        const float* __restrict__ a2s, const float* __restrict__ a2d,
                        char* __restrict__ rec2, float* __restrict__ ed2) {
    __shared__ float Ws[64 * 64];
    __shared__ float hs[16][64];
    int t = threadIdx.x;
    int n0 = blockIdx.x * 16;
    #pragma unroll
    for (int i = 0; i < 4; i++) {
        int flat = i * 256 + t;
        *(float4*)(Ws + flat * 4) = *(const float4*)(W2 + flat * 4);
    }
    #pragma unroll
    for (int i = 0; i < 4; i++) {
        int flat = i * 256 + t;
        hs[flat >> 6][flat & 63] = h2[(size_t)(n0 + (flat >> 6)) * 64 + (flat & 63)];
    }
    __syncthreads();
    int wv = t >> 6, lane = t & 63;
    float as = a2s[lane], ad = a2d[lane];
    #pragma unroll
    for (int j = 0; j < 4; j++) {
        int nl = wv * 4 + j;
        int n = n0 + nl;
        float acc = 0.f;
        #pragma unroll
        for (int k = 0; k < 64; k++) acc += hs[nl][k] * Ws[k * 64 + lane];
        char* r = rec2 + (size_t)n * REC2;
        *(unsigned short*)(r + 16 + lane * 2) = f2bf(acc);
        float s = acc * as;
        float dd = acc * ad;
        #pragma unroll
        for (int off = 1; off < 64; off <<= 1) {
            s += __shfl_xor(s, off);
            dd += __shfl_xor(dd, off);
        }
        if (lane == 0) { *(float*)r = s; ed2[n] = dd; }
    }
}

// ---------------- layer-2 aggregation: GROUP-PER-NODE + fused final softmax ----------
__launch_bounds__(256)
__global__ void k_agg2(const char* __restrict__ rec2, const float* __restrict__ ed2,
                       const int* __restrict__ rowptr, const int* __restrict__ deg,
                       const int* __restrict__ col, float* __restrict__ out) {
    int tid = blockIdx.x * 256 + threadIdx.x;
    int n = tid >> 3, q = tid & 7;
    if (n >= N_NODES) return;
    int d = deg[n];
    int start = rowptr[n] - d;
    float edn = ed2[n];

    float den = 0.f;
    float acc[8] = {};
    for (int e = 0; e < d; e += 2) {
        int sv0 = col[start + e];
        int sv1 = col[start + min(e + 1, d - 1)];
        const char* r0 = rec2 + (size_t)sv0 * REC2;
        const char* r1 = rec2 + (size_t)sv1 * REC2;
        float x0 = *(const float*)r0 + edn;
        float x1 = *(const float*)r1 + edn;
        uint4 u0 = *(const uint4*)(r0 + 16 + q * 16);
        uint4 u1 = *(const uint4*)(r1 + 16 + q * 16);
        x0 = x0 > 0.f ? x0 : SLOPE * x0;
        x1 = x1 > 0.f ? x1 : SLOPE * x1;
        float w0 = __expf(x0);
        float w1 = (e + 1 < d) ? __expf(x1) : 0.f;
        den += w0 + w1;
        float f0[8] = {bf_lo(u0.x), bf_hi(u0.x), bf_lo(u0.y), bf_hi(u0.y),
                       bf_lo(u0.z), bf_hi(u0.z), bf_lo(u0.w), bf_hi(u0.w)};
        float f1[8] = {bf_lo(u1.x), bf_hi(u1.x), bf_lo(u1.y), bf_hi(u1.y),
                       bf_lo(u1.z), bf_hi(u1.z), bf_lo(u1.w), bf_hi(u1.w)};
        #pragma unroll
        for (int j = 0; j < 8; j++) acc[j] += w0 * f0[j] + w1 * f1[j];
    }
    float inv = 1.f / (den + 1e-10f);
    float o[8];
    #pragma unroll
    for (int j = 0; j < 8; j++) o[j] = acc[j] * inv;
    // softmax over 64 classes spread across the 8-lane group (xor 1,2,4 stays in-group)
    float mx = o[0];
    #pragma unroll
    for (int j = 1; j < 8; j++) mx = fmaxf(mx, o[j]);
    mx = fmaxf(mx, __shfl_xor(mx, 1));
    mx = fmaxf(mx, __shfl_xor(mx, 2));
    mx = fmaxf(mx, __shfl_xor(mx, 4));
    float e8[8], sm = 0.f;
    #pragma unroll
    for (int j = 0; j < 8; j++) { e8[j] = __expf(o[j] - mx); sm += e8[j]; }
    sm += __shfl_xor(sm, 1);
    sm += __shfl_xor(sm, 2);
    sm += __shfl_xor(sm, 4);
    float inv2 = 1.f / sm;
    float4* op = (float4*)(out + (size_t)n * 64 + q * 8);
    op[0] = make_float4(e8[0] * inv2, e8[1] * inv2, e8[2] * inv2, e8[3] * inv2);
    op[1] = make_float4(e8[4] * inv2, e8[5] * inv2, e8[6] * inv2, e8[7] * inv2);
}

// ---------------- launcher (8 dispatches) ----------------
extern "C" void kernel_launch(void* const* d_in, const int* in_sizes, int n_in,
                              void* d_out, int out_size, void* d_ws, size_t ws_size,
                              hipStream_t stream) {
    const float* X   = (const float*)d_in[0];
    const float* W1  = (const float*)d_in[1];
    const float* a1s = (const float*)d_in[2];
    const float* a1d = (const float*)d_in[3];
    const float* W2  = (const float*)d_in[4];
    const float* a2s = (const float*)d_in[5];
    const float* a2d = (const float*)d_in[6];
    const int*   src = (const int*)d_in[7];
    const int*   dst = (const int*)d_in[8];
    float* out = (float*)d_out;

    char* w = (char*)d_ws;
    size_t off = 0;
    auto alloc = [&](size_t bytes) {
        void* p = w + off;
        off += (bytes + 255) & ~(size_t)255;
        return p;
    };
    unsigned short* Bh  = (unsigned short*)alloc((size_t)C1 * F_IN * 2);
    unsigned short* Bl  = (unsigned short*)alloc((size_t)C1 * F_IN * 2);
    char*  rec1  = (char*)alloc((size_t)N_NODES * REC1);
    char*  rec2  = (char*)alloc((size_t)N_NODES * REC2);
    float* h2    = (float*)alloc((size_t)N_NODES * 64 * 4);
    float* ed1   = (float*)alloc((size_t)N_NODES * 8 * 4);
    float* ed2   = (float*)alloc((size_t)N_NODES * 4);
    int*   deg   = (int*)alloc((size_t)N_NODES * 4);
    int*   rowptr= (int*)alloc((size_t)N_NODES * 4);
    int*   col   = (int*)alloc((size_t)N_EDGES * 4);
    int*   bsums = (int*)alloc(256 * 4);

    hipMemsetAsync(deg, 0, (size_t)N_NODES * 4, stream);

    k_histwt<<<NBLK_HIST + NBLK_WT, 256, 0, stream>>>(dst, deg, W1, Bh, Bl);
    k_scan1<<<NBLK_SCAN, 256, 0, stream>>>(deg, rowptr, bsums);
    k_scan23<<<NBLK_SCAN, 256, 0, stream>>>(bsums, rowptr);

    // fused: even blocks = GEMM1+pack, odd blocks = CSR scatter (latency hidden)
    k_gemm1p<<<NBLK_G1 * 2, 256, 0, stream>>>(X, Bh, Bl, a1s, a1d, rec1, ed1,
                                              src, dst, rowptr, col);
    k_agg1<<<(N_NODES * 8 + 255) / 256, 256, 0, stream>>>(rec1, ed1, rowptr, deg, col, h2);
    k_gemm2<<<N_NODES / 16, 256, 0, stream>>>(h2, W2, a2s, a2d, rec2, ed2);
    k_agg2<<<(N_NODES * 8 + 255) / 256, 256, 0, stream>>>(rec2, ed2, rowptr, deg, col, out);
}

// Round 2
// 283.160 us; speedup vs baseline: 1.2195x; 1.1405x over previous
//
#include <hip/hip_runtime.h>
#include <math.h>

#define N_NODES 50000
#define N_EDGES 800000
#define F_IN    512
#define H1      8
#define F_HID   8
#define C1      64      // H1*F_HID
#define NLAB    64
#define SLOPE   0.2f
#define MAXDEG  64      // multinomial(800K,50K): mean 16, max ~35; 64 is safe

#define NBLK_WT   128   // 64*512/256 W1-split blocks
#define NBLK_Z    196   // ceil(50000/256) deg-zero blocks
#define NBLK_G1   782   // (50000+63)/64 gemm1 row-blocks
#define NBLK_SC  3128   // NBLK_G1*4 scatter blocks (1 edge/thread, >= 3125 needed)
#define REC1     160    // [es1: 8 f32 | Wh1: 64 bf16] (2 cache lines)
#define REC2     144    // [es2: f32, pad | Wh2: 64 bf16]

typedef __attribute__((ext_vector_type(8))) short short8;
typedef __attribute__((ext_vector_type(4))) float f32x4;

__device__ __forceinline__ float bf_lo(unsigned u) { return __uint_as_float(u << 16); }
__device__ __forceinline__ float bf_hi(unsigned u) { return __uint_as_float(u & 0xFFFF0000u); }
__device__ __forceinline__ unsigned short f2bf(float x) {
    unsigned bits = __float_as_uint(x);
    return (unsigned short)((bits + 0x7FFF + ((bits >> 16) & 1)) >> 16);   // RNE
}

// ---------------- prep: W1 bf16 split (blocks 0..127) + deg zero (128..323) ----------
__global__ void k_prep(const float* __restrict__ W1, unsigned short* __restrict__ Bh,
                       unsigned short* __restrict__ Bl, int* __restrict__ deg) {
    int b = blockIdx.x;
    if (b < NBLK_WT) {
        int i = b * 256 + threadIdx.x;   // 0..32767
        int c = i >> 9, f = i & 511;
        float v = W1[(c >> 3) * (F_IN * F_HID) + f * F_HID + (c & 7)];
        unsigned bits = __float_as_uint(v);
        float r = v - __uint_as_float(bits & 0xFFFF0000u);
        Bh[i] = (unsigned short)(bits >> 16);
        Bl[i] = (unsigned short)(__float_as_uint(r) >> 16);
    } else {
        int i = (b - NBLK_WT) * 256 + threadIdx.x;
        if (i < N_NODES) deg[i] = 0;
    }
}

// ---------------- GEMM1 + es/ed/record pack, FUSED with padded-CSR scatter ----------
// Grid = 5*NBLK_G1. Blocks with b%5==0 run the GEMM path (row block = b/5);
// the other 4/5 run the combined histogram+scatter: one atomicAdd(&deg,1)
// returns the slot in colPad[d*64+slot]. deg ends at exact degree.
// 1 edge/thread for max TLP (the scatter is latency-bound).
__launch_bounds__(256)
__global__ void k_gemm1f(const float* __restrict__ X, const unsigned short* __restrict__ Bh,
                         const unsigned short* __restrict__ Bl, const float* __restrict__ a_s,
                         const float* __restrict__ a_d, char* __restrict__ rec,
                         float* __restrict__ ed,
                         const int* __restrict__ src, const int* __restrict__ dst,
                         int* __restrict__ deg, int* __restrict__ colPad) {
    __shared__ unsigned short sBh[64][136];
    __shared__ unsigned short sBl[64][136];

    const int b = blockIdx.x;
    const int g = b / 5, r = b % 5;
    if (r) {                       // ---- scatter path (block-uniform branch) ----
        int e = (g * 4 + (r - 1)) * 256 + threadIdx.x;
        if (e >= N_EDGES) return;
        int d = dst[e];
        int s = src[e];
        int slot = atomicAdd(&deg[d], 1);
        colPad[(d << 6) | min(slot, MAXDEG - 1)] = s;
        return;
    }

    const int t = threadIdx.x;
    const int lane = t & 63, w = t >> 6;
    const int r0 = g * 64 + w * 16;
    const int m = lane & 15, quad = lane >> 4;
    int row = r0 + m; if (row >= N_NODES) row = N_NODES - 1;
    const float* xrow = X + (size_t)row * F_IN + quad * 8;

    const int sc = t >> 2;
    const int sp = t & 3;

    f32x4 acc[4] = {};
    float4 pxa[4], pxb[4];
    #pragma unroll
    for (int i = 0; i < 4; i++) {
        pxa[i] = *(const float4*)(xrow + i * 32);
        pxb[i] = *(const float4*)(xrow + i * 32 + 4);
    }

    for (int chunk = 0; chunk < 4; chunk++) {
        const int k0 = chunk * 128;
        if (chunk) __syncthreads();
        #pragma unroll
        for (int i = 0; i < 4; i++) {
            *(short8*)(&sBh[sc][sp * 32 + i * 8]) =
                *(const short8*)(Bh + sc * F_IN + k0 + sp * 32 + i * 8);
            *(short8*)(&sBl[sc][sp * 32 + i * 8]) =
                *(const short8*)(Bl + sc * F_IN + k0 + sp * 32 + i * 8);
        }
        __syncthreads();
        #pragma unroll
        for (int i = 0; i < 4; i++) {
            float xs[8] = {pxa[i].x, pxa[i].y, pxa[i].z, pxa[i].w,
                           pxb[i].x, pxb[i].y, pxb[i].z, pxb[i].w};
            if (chunk < 3) {
                const int ktn = k0 + 128 + i * 32;
                pxa[i] = *(const float4*)(xrow + ktn);
                pxb[i] = *(const float4*)(xrow + ktn + 4);
            }
            short8 ah, al;
            #pragma unroll
            for (int j = 0; j < 8; j++) {
                unsigned bits = __float_as_uint(xs[j]);
                float rr = xs[j] - __uint_as_float(bits & 0xFFFF0000u);
                ah[j] = (short)(bits >> 16);
                al[j] = (short)(__float_as_uint(rr) >> 16);
            }
            #pragma unroll
            for (int s = 0; s < 4; s++) {
                short8 bh = *(const short8*)(&sBh[s * 16 + m][i * 32 + quad * 8]);
                short8 bl = *(const short8*)(&sBl[s * 16 + m][i * 32 + quad * 8]);
                acc[s] = __builtin_amdgcn_mfma_f32_16x16x32_bf16(al, bh, acc[s], 0, 0, 0);
                acc[s] = __builtin_amdgcn_mfma_f32_16x16x32_bf16(ah, bl, acc[s], 0, 0, 0);
                acc[s] = __builtin_amdgcn_mfma_f32_16x16x32_bf16(ah, bh, acc[s], 0, 0, 0);
            }
        }
    }
    __syncthreads();
    unsigned short* sWh = &sBh[0][0] + w * 1024;
    #pragma unroll
    for (int s = 0; s < 4; s++)
        #pragma unroll
        for (int reg = 0; reg < 4; reg++)
            sWh[(quad * 4 + reg) * 64 + s * 16 + m] = f2bf(acc[s][reg]);
    __syncthreads();
    const int rr = lane & 15, p = lane >> 4;
    const int n = r0 + rr;
    if (n >= N_NODES) return;
    float es2v[2], edv[2];
    #pragma unroll
    for (int hh = 0; hh < 2; hh++) {
        int h = 2 * p + hh;
        float s = 0.f, dsum = 0.f;
        #pragma unroll
        for (int j = 0; j < 8; j++) {
            float v = __uint_as_float((unsigned)sWh[rr * 64 + h * 8 + j] << 16);
            s += v * a_s[h * 8 + j];
            dsum += v * a_d[h * 8 + j];
        }
        es2v[hh] = s; edv[hh] = dsum;
    }
    char* rp = rec + (size_t)n * REC1;
    *(float2*)(rp + p * 8) = make_float2(es2v[0], es2v[1]);
    *(short8*)(rp + 32 + p * 32)      = *(const short8*)(sWh + rr * 64 + p * 16);
    *(short8*)(rp + 32 + p * 32 + 16) = *(const short8*)(sWh + rr * 64 + p * 16 + 8);
    *(float2*)(ed + n * 8 + 2 * p) = make_float2(edv[0], edv[1]);
}

// ---------------- layer-1 aggregation: GROUP-PER-NODE (8 lanes/node) ----------------
// lane q of each 8-lane group owns head q (= channels 8q..8q+7). Padded CSR:
// neighbors of n live at colPad[n*64 .. n*64+deg). 2x edge unroll for ILP.
__launch_bounds__(256)
__global__ void k_agg1(const char* __restrict__ rec, const float* __restrict__ ed,
                       const int* __restrict__ deg, const int* __restrict__ colPad,
                       float* __restrict__ h2) {
    int tid = blockIdx.x * 256 + threadIdx.x;
    int n = tid >> 3, q = tid & 7;
    if (n >= N_NODES) return;
    int d = deg[n];
    int start = n << 6;
    float edq = ed[n * 8 + q];

    float den = 0.f;
    float acc[8] = {};
    for (int e = 0; e < d; e += 2) {
        int sv0 = colPad[start + e];
        int sv1 = colPad[start + min(e + 1, d - 1)];
        const char* r0 = rec + (size_t)sv0 * REC1;
        const char* r1 = rec + (size_t)sv1 * REC1;
        float x0 = *(const float*)(r0 + q * 4) + edq;
        float x1 = *(const float*)(r1 + q * 4) + edq;
        uint4 u0 = *(const uint4*)(r0 + 32 + q * 16);
        uint4 u1 = *(const uint4*)(r1 + 32 + q * 16);
        x0 = x0 > 0.f ? x0 : SLOPE * x0;
        x1 = x1 > 0.f ? x1 : SLOPE * x1;
        float w0 = __expf(x0);
        float w1 = (e + 1 < d) ? __expf(x1) : 0.f;
        den += w0 + w1;
        float f0[8] = {bf_lo(u0.x), bf_hi(u0.x), bf_lo(u0.y), bf_hi(u0.y),
                       bf_lo(u0.z), bf_hi(u0.z), bf_lo(u0.w), bf_hi(u0.w)};
        float f1[8] = {bf_lo(u1.x), bf_hi(u1.x), bf_lo(u1.y), bf_hi(u1.y),
                       bf_lo(u1.z), bf_hi(u1.z), bf_lo(u1.w), bf_hi(u1.w)};
        #pragma unroll
        for (int j = 0; j < 8; j++) acc[j] += w0 * f0[j] + w1 * f1[j];
    }
    float inv = 1.f / (den + 1e-10f);
    float o[8];
    #pragma unroll
    for (int j = 0; j < 8; j++) {
        float v = acc[j] * inv;
        o[j] = v > 0.f ? v : expm1f(v);   // fused ELU
    }
    float4* hp = (float4*)(h2 + (size_t)n * 64 + q * 8);
    hp[0] = make_float4(o[0], o[1], o[2], o[3]);
    hp[1] = make_float4(o[4], o[5], o[6], o[7]);
}

// ---------------- GEMM2 (K=64), 16 nodes/block; writes record2 + ed2 ----------------
__launch_bounds__(256)
__global__ void k_gemm2(const float* __restrict__ h2, const float* __restrict__ W2,
                        const float* __restrict__ a2s, const float* __restrict__ a2d,
                        char* __restrict__ rec2, float* __restrict__ ed2) {
    __shared__ float Ws[64 * 64];
    __shared__ float hs[16][64];
    int t = threadIdx.x;
    int n0 = blockIdx.x * 16;
    #pragma unroll
    for (int i = 0; i < 4; i++) {
        int flat = i * 256 + t;
        *(float4*)(Ws + flat * 4) = *(const float4*)(W2 + flat * 4);
    }
    #pragma unroll
    for (int i = 0; i < 4; i++) {
        int flat = i * 256 + t;
        hs[flat >> 6][flat & 63] = h2[(size_t)(n0 + (flat >> 6)) * 64 + (flat & 63)];
    }
    __syncthreads();
    int wv = t >> 6, lane = t & 63;
    float as = a2s[lane], ad = a2d[lane];
    #pragma unroll
    for (int j = 0; j < 4; j++) {
        int nl = wv * 4 + j;
        int n = n0 + nl;
        float acc = 0.f;
        #pragma unroll
        for (int k = 0; k < 64; k++) acc += hs[nl][k] * Ws[k * 64 + lane];
        char* r = rec2 + (size_t)n * REC2;
        *(unsigned short*)(r + 16 + lane * 2) = f2bf(acc);
        float s = acc * as;
        float dd = acc * ad;
        #pragma unroll
        for (int off = 1; off < 64; off <<= 1) {
            s += __shfl_xor(s, off);
            dd += __shfl_xor(dd, off);
        }
        if (lane == 0) { *(float*)r = s; ed2[n] = dd; }
    }
}

// ---------------- layer-2 aggregation: GROUP-PER-NODE + fused final softmax ----------
__launch_bounds__(256)
__global__ void k_agg2(const char* __restrict__ rec2, const float* __restrict__ ed2,
                       const int* __restrict__ deg, const int* __restrict__ colPad,
                       float* __restrict__ out) {
    int tid = blockIdx.x * 256 + threadIdx.x;
    int n = tid >> 3, q = tid & 7;
    if (n >= N_NODES) return;
    int d = deg[n];
    int start = n << 6;
    float edn = ed2[n];

    float den = 0.f;
    float acc[8] = {};
    for (int e = 0; e < d; e += 2) {
        int sv0 = colPad[start + e];
        int sv1 = colPad[start + min(e + 1, d - 1)];
        const char* r0 = rec2 + (size_t)sv0 * REC2;
        const char* r1 = rec2 + (size_t)sv1 * REC2;
        float x0 = *(const float*)r0 + edn;
        float x1 = *(const float*)r1 + edn;
        uint4 u0 = *(const uint4*)(r0 + 16 + q * 16);
        uint4 u1 = *(const uint4*)(r1 + 16 + q * 16);
        x0 = x0 > 0.f ? x0 : SLOPE * x0;
        x1 = x1 > 0.f ? x1 : SLOPE * x1;
        float w0 = __expf(x0);
        float w1 = (e + 1 < d) ? __expf(x1) : 0.f;
        den += w0 + w1;
        float f0[8] = {bf_lo(u0.x), bf_hi(u0.x), bf_lo(u0.y), bf_hi(u0.y),
                       bf_lo(u0.z), bf_hi(u0.z), bf_lo(u0.w), bf_hi(u0.w)};
        float f1[8] = {bf_lo(u1.x), bf_hi(u1.x), bf_lo(u1.y), bf_hi(u1.y),
                       bf_lo(u1.z), bf_hi(u1.z), bf_lo(u1.w), bf_hi(u1.w)};
        #pragma unroll
        for (int j = 0; j < 8; j++) acc[j] += w0 * f0[j] + w1 * f1[j];
    }
    float inv = 1.f / (den + 1e-10f);
    float o[8];
    #pragma unroll
    for (int j = 0; j < 8; j++) o[j] = acc[j] * inv;
    // softmax over 64 classes spread across the 8-lane group (xor 1,2,4 stays in-group)
    float mx = o[0];
    #pragma unroll
    for (int j = 1; j < 8; j++) mx = fmaxf(mx, o[j]);
    mx = fmaxf(mx, __shfl_xor(mx, 1));
    mx = fmaxf(mx, __shfl_xor(mx, 2));
    mx = fmaxf(mx, __shfl_xor(mx, 4));
    float e8[8], sm = 0.f;
    #pragma unroll
    for (int j = 0; j < 8; j++) { e8[j] = __expf(o[j] - mx); sm += e8[j]; }
    sm += __shfl_xor(sm, 1);
    sm += __shfl_xor(sm, 2);
    sm += __shfl_xor(sm, 4);
    float inv2 = 1.f / sm;
    float4* op = (float4*)(out + (size_t)n * 64 + q * 8);
    op[0] = make_float4(e8[0] * inv2, e8[1] * inv2, e8[2] * inv2, e8[3] * inv2);
    op[1] = make_float4(e8[4] * inv2, e8[5] * inv2, e8[6] * inv2, e8[7] * inv2);
}

// ---------------- launcher (5 dispatches, no memset) ----------------
extern "C" void kernel_launch(void* const* d_in, const int* in_sizes, int n_in,
                              void* d_out, int out_size, void* d_ws, size_t ws_size,
                              hipStream_t stream) {
    const float* X   = (const float*)d_in[0];
    const float* W1  = (const float*)d_in[1];
    const float* a1s = (const float*)d_in[2];
    const float* a1d = (const float*)d_in[3];
    const float* W2  = (const float*)d_in[4];
    const float* a2s = (const float*)d_in[5];
    const float* a2d = (const float*)d_in[6];
    const int*   src = (const int*)d_in[7];
    const int*   dst = (const int*)d_in[8];
    float* out = (float*)d_out;

    char* w = (char*)d_ws;
    size_t off = 0;
    auto alloc = [&](size_t bytes) {
        void* p = w + off;
        off += (bytes + 255) & ~(size_t)255;
        return p;
    };
    unsigned short* Bh  = (unsigned short*)alloc((size_t)C1 * F_IN * 2);
    unsigned short* Bl  = (unsigned short*)alloc((size_t)C1 * F_IN * 2);
    char*  rec1  = (char*)alloc((size_t)N_NODES * REC1);
    char*  rec2  = (char*)alloc((size_t)N_NODES * REC2);
    float* h2    = (float*)alloc((size_t)N_NODES * 64 * 4);
    float* ed1   = (float*)alloc((size_t)N_NODES * 8 * 4);
    float* ed2   = (float*)alloc((size_t)N_NODES * 4);
    int*   deg   = (int*)alloc((size_t)N_NODES * 4);
    int*   colPad= (int*)alloc((size_t)N_NODES * MAXDEG * 4);

    k_prep<<<NBLK_WT + NBLK_Z, 256, 0, stream>>>(W1, Bh, Bl, deg);
    // fused: 1/5 blocks = GEMM1+pack, 4/5 = histogram+scatter (1 edge/thread)
    k_gemm1f<<<NBLK_G1 * 5, 256, 0, stream>>>(X, Bh, Bl, a1s, a1d, rec1, ed1,
                                              src, dst, deg, colPad);
    k_agg1<<<(N_NODES * 8 + 255) / 256, 256, 0, stream>>>(rec1, ed1, deg, colPad, h2);
    k_gemm2<<<N_NODES / 16, 256, 0, stream>>>(h2, W2, a2s, a2d, rec2, ed2);
    k_agg2<<<(N_NODES * 8 + 255) / 256, 256, 0, stream>>>(rec2, ed2, deg, colPad, out);
}

// Round 3
// 280.952 us; speedup vs baseline: 1.2291x; 1.0079x over previous
//
#include <hip/hip_runtime.h>
#include <math.h>

#define N_NODES 50000
#define N_EDGES 800000
#define F_IN    512
#define H1      8
#define F_HID   8
#define C1      64      // H1*F_HID
#define NLAB    64
#define SLOPE   0.2f
#define MAXDEG  64      // multinomial(800K,50K): mean 16, max ~35; 64 is safe
#define DEGS    16      // deg stride in ints: 1 counter per 64B line (atomic spread)

#define NBLK_WT   128   // 64*512/256 W1-split blocks
#define NBLK_Z    782   // 50000*16 ints / (256 thr * 4 ints) zero blocks
#define NBLK_G1   782   // (50000+63)/64 gemm1 row-blocks
#define REC1     160    // [es1: 8 f32 | Wh1: 64 bf16] (2 cache lines)
#define REC2     144    // [es2: f32, pad | Wh2: 64 bf16]

typedef __attribute__((ext_vector_type(8))) short short8;
typedef __attribute__((ext_vector_type(4))) float f32x4;

__device__ __forceinline__ float bf_lo(unsigned u) { return __uint_as_float(u << 16); }
__device__ __forceinline__ float bf_hi(unsigned u) { return __uint_as_float(u & 0xFFFF0000u); }
__device__ __forceinline__ unsigned short f2bf(float x) {
    unsigned bits = __float_as_uint(x);
    return (unsigned short)((bits + 0x7FFF + ((bits >> 16) & 1)) >> 16);   // RNE
}

// ------- prep: W1 bf16 split (blocks 0..127) + deg zero via int4 (128..909) -------
__global__ void k_prep(const float* __restrict__ W1, unsigned short* __restrict__ Bh,
                       unsigned short* __restrict__ Bl, int* __restrict__ deg) {
    int b = blockIdx.x;
    if (b < NBLK_WT) {
        int i = b * 256 + threadIdx.x;   // 0..32767
        int c = i >> 9, f = i & 511;
        float v = W1[(c >> 3) * (F_IN * F_HID) + f * F_HID + (c & 7)];
        unsigned bits = __float_as_uint(v);
        float r = v - __uint_as_float(bits & 0xFFFF0000u);
        Bh[i] = (unsigned short)(bits >> 16);
        Bl[i] = (unsigned short)(__float_as_uint(r) >> 16);
    } else {
        int i = (b - NBLK_WT) * 256 + threadIdx.x;   // int4 index
        if (i < N_NODES * DEGS / 4)
            *(int4*)(deg + i * 4) = make_int4(0, 0, 0, 0);
    }
}

// ---------------- GEMM1 + es/ed/record pack, FUSED with padded-CSR scatter ----------
// Grid = 5*NBLK_G1. Blocks with b%5==0 run the GEMM path (row block = b/5);
// the other 4/5 run the combined histogram+scatter: one atomicAdd on a
// line-padded counter (deg[d*16]) returns the slot in colPad[d*64+slot].
__launch_bounds__(256)
__global__ void k_gemm1f(const float* __restrict__ X, const unsigned short* __restrict__ Bh,
                         const unsigned short* __restrict__ Bl, const float* __restrict__ a_s,
                         const float* __restrict__ a_d, char* __restrict__ rec,
                         float* __restrict__ ed,
                         const int* __restrict__ src, const int* __restrict__ dst,
                         int* __restrict__ deg, int* __restrict__ colPad) {
    __shared__ unsigned short sBh[64][136];
    __shared__ unsigned short sBl[64][136];

    const int b = blockIdx.x;
    const int g = b / 5, r = b % 5;
    if (r) {                       // ---- scatter path (block-uniform branch) ----
        int e = (g * 4 + (r - 1)) * 256 + threadIdx.x;
        if (e >= N_EDGES) return;
        int d = dst[e];
        int s = src[e];
        int slot = atomicAdd(&deg[d << 4], 1);
        colPad[(d << 6) | min(slot, MAXDEG - 1)] = s;
        return;
    }

    const int t = threadIdx.x;
    const int lane = t & 63, w = t >> 6;
    const int r0 = g * 64 + w * 16;
    const int m = lane & 15, quad = lane >> 4;
    int row = r0 + m; if (row >= N_NODES) row = N_NODES - 1;
    const float* xrow = X + (size_t)row * F_IN + quad * 8;

    const int sc = t >> 2;
    const int sp = t & 3;

    f32x4 acc[4] = {};
    float4 pxa[4], pxb[4];
    #pragma unroll
    for (int i = 0; i < 4; i++) {
        pxa[i] = *(const float4*)(xrow + i * 32);
        pxb[i] = *(const float4*)(xrow + i * 32 + 4);
    }

    for (int chunk = 0; chunk < 4; chunk++) {
        const int k0 = chunk * 128;
        if (chunk) __syncthreads();
        #pragma unroll
        for (int i = 0; i < 4; i++) {
            *(short8*)(&sBh[sc][sp * 32 + i * 8]) =
                *(const short8*)(Bh + sc * F_IN + k0 + sp * 32 + i * 8);
            *(short8*)(&sBl[sc][sp * 32 + i * 8]) =
                *(const short8*)(Bl + sc * F_IN + k0 + sp * 32 + i * 8);
        }
        __syncthreads();
        #pragma unroll
        for (int i = 0; i < 4; i++) {
            float xs[8] = {pxa[i].x, pxa[i].y, pxa[i].z, pxa[i].w,
                           pxb[i].x, pxb[i].y, pxb[i].z, pxb[i].w};
            if (chunk < 3) {
                const int ktn = k0 + 128 + i * 32;
                pxa[i] = *(const float4*)(xrow + ktn);
                pxb[i] = *(const float4*)(xrow + ktn + 4);
            }
            short8 ah, al;
            #pragma unroll
            for (int j = 0; j < 8; j++) {
                unsigned bits = __float_as_uint(xs[j]);
                float rr = xs[j] - __uint_as_float(bits & 0xFFFF0000u);
                ah[j] = (short)(bits >> 16);
                al[j] = (short)(__float_as_uint(rr) >> 16);
            }
            #pragma unroll
            for (int s = 0; s < 4; s++) {
                short8 bh = *(const short8*)(&sBh[s * 16 + m][i * 32 + quad * 8]);
                short8 bl = *(const short8*)(&sBl[s * 16 + m][i * 32 + quad * 8]);
                acc[s] = __builtin_amdgcn_mfma_f32_16x16x32_bf16(al, bh, acc[s], 0, 0, 0);
                acc[s] = __builtin_amdgcn_mfma_f32_16x16x32_bf16(ah, bl, acc[s], 0, 0, 0);
                acc[s] = __builtin_amdgcn_mfma_f32_16x16x32_bf16(ah, bh, acc[s], 0, 0, 0);
            }
        }
    }
    __syncthreads();
    unsigned short* sWh = &sBh[0][0] + w * 1024;
    #pragma unroll
    for (int s = 0; s < 4; s++)
        #pragma unroll
        for (int reg = 0; reg < 4; reg++)
            sWh[(quad * 4 + reg) * 64 + s * 16 + m] = f2bf(acc[s][reg]);
    __syncthreads();
    const int rr = lane & 15, p = lane >> 4;
    const int n = r0 + rr;
    if (n >= N_NODES) return;
    float es2v[2], edv[2];
    #pragma unroll
    for (int hh = 0; hh < 2; hh++) {
        int h = 2 * p + hh;
        float s = 0.f, dsum = 0.f;
        #pragma unroll
        for (int j = 0; j < 8; j++) {
            float v = __uint_as_float((unsigned)sWh[rr * 64 + h * 8 + j] << 16);
            s += v * a_s[h * 8 + j];
            dsum += v * a_d[h * 8 + j];
        }
        es2v[hh] = s; edv[hh] = dsum;
    }
    char* rp = rec + (size_t)n * REC1;
    *(float2*)(rp + p * 8) = make_float2(es2v[0], es2v[1]);
    *(short8*)(rp + 32 + p * 32)      = *(const short8*)(sWh + rr * 64 + p * 16);
    *(short8*)(rp + 32 + p * 32 + 16) = *(const short8*)(sWh + rr * 64 + p * 16 + 8);
    *(float2*)(ed + n * 8 + 2 * p) = make_float2(edv[0], edv[1]);
}

// -------- FUSED layer-1 aggregation (8 lanes/node) + GEMM2 (K=64) --------
// 32 nodes/block. Phase A: group-per-node softmax-aggregate + ELU -> hs LDS.
// Phase B: per-wave GEMM vs W2 (staged in LDS), rec2/ed2 pack. h2 never
// touches HBM.
__launch_bounds__(256)
__global__ void k_agg1g2(const char* __restrict__ rec, const float* __restrict__ ed,
                         const int* __restrict__ deg, const int* __restrict__ colPad,
                         const float* __restrict__ W2, const float* __restrict__ a2s,
                         const float* __restrict__ a2d,
                         char* __restrict__ rec2, float* __restrict__ ed2) {
    __shared__ float Ws[64 * 64];    // 16KB
    __shared__ float hs[32][64];     // 8KB
    const int t = threadIdx.x;
    #pragma unroll
    for (int i = 0; i < 4; i++) {
        int flat = i * 256 + t;
        *(float4*)(Ws + flat * 4) = *(const float4*)(W2 + flat * 4);
    }
    const int n0 = blockIdx.x * 32;
    const int n = n0 + (t >> 3), q = t & 7;

    float o[8] = {};
    if (n < N_NODES) {
        int d = deg[n << 4];
        int start = n << 6;
        float edq = ed[n * 8 + q];
        float den = 0.f;
        float acc[8] = {};
        for (int e = 0; e < d; e += 2) {
            int sv0 = colPad[start + e];
            int sv1 = colPad[start + min(e + 1, d - 1)];
            const char* r0 = rec + (size_t)sv0 * REC1;
            const char* r1 = rec + (size_t)sv1 * REC1;
            float x0 = *(const float*)(r0 + q * 4) + edq;
            float x1 = *(const float*)(r1 + q * 4) + edq;
            uint4 u0 = *(const uint4*)(r0 + 32 + q * 16);
            uint4 u1 = *(const uint4*)(r1 + 32 + q * 16);
            x0 = x0 > 0.f ? x0 : SLOPE * x0;
            x1 = x1 > 0.f ? x1 : SLOPE * x1;
            float w0 = __expf(x0);
            float w1 = (e + 1 < d) ? __expf(x1) : 0.f;
            den += w0 + w1;
            float f0[8] = {bf_lo(u0.x), bf_hi(u0.x), bf_lo(u0.y), bf_hi(u0.y),
                           bf_lo(u0.z), bf_hi(u0.z), bf_lo(u0.w), bf_hi(u0.w)};
            float f1[8] = {bf_lo(u1.x), bf_hi(u1.x), bf_lo(u1.y), bf_hi(u1.y),
                           bf_lo(u1.z), bf_hi(u1.z), bf_lo(u1.w), bf_hi(u1.w)};
            #pragma unroll
            for (int j = 0; j < 8; j++) acc[j] += w0 * f0[j] + w1 * f1[j];
        }
        float inv = 1.f / (den + 1e-10f);
        #pragma unroll
        for (int j = 0; j < 8; j++) {
            float v = acc[j] * inv;
            o[j] = v > 0.f ? v : expm1f(v);   // fused ELU
        }
    }
    float4* hp = (float4*)(&hs[t >> 3][q * 8]);
    hp[0] = make_float4(o[0], o[1], o[2], o[3]);
    hp[1] = make_float4(o[4], o[5], o[6], o[7]);
    __syncthreads();

    // ---- GEMM2 phase: wave wv handles 8 nodes, lane = output class ----
    const int wv = t >> 6, lane = t & 63;
    float as = a2s[lane], ad = a2d[lane];
    #pragma unroll
    for (int j = 0; j < 8; j++) {
        int nl = wv * 8 + j;
        int nn = n0 + nl;
        if (nn >= N_NODES) break;
        float acc = 0.f;
        #pragma unroll
        for (int k = 0; k < 64; k++) acc += hs[nl][k] * Ws[k * 64 + lane];
        char* r = rec2 + (size_t)nn * REC2;
        *(unsigned short*)(r + 16 + lane * 2) = f2bf(acc);
        float s = acc * as;
        float dd = acc * ad;
        #pragma unroll
        for (int off = 1; off < 64; off <<= 1) {
            s += __shfl_xor(s, off);
            dd += __shfl_xor(dd, off);
        }
        if (lane == 0) { *(float*)r = s; ed2[nn] = dd; }
    }
}

// ---------------- layer-2 aggregation: GROUP-PER-NODE + fused final softmax ----------
__launch_bounds__(256)
__global__ void k_agg2(const char* __restrict__ rec2, const float* __restrict__ ed2,
                       const int* __restrict__ deg, const int* __restrict__ colPad,
                       float* __restrict__ out) {
    int tid = blockIdx.x * 256 + threadIdx.x;
    int n = tid >> 3, q = tid & 7;
    if (n >= N_NODES) return;
    int d = deg[n << 4];
    int start = n << 6;
    float edn = ed2[n];

    float den = 0.f;
    float acc[8] = {};
    for (int e = 0; e < d; e += 2) {
        int sv0 = colPad[start + e];
        int sv1 = colPad[start + min(e + 1, d - 1)];
        const char* r0 = rec2 + (size_t)sv0 * REC2;
        const char* r1 = rec2 + (size_t)sv1 * REC2;
        float x0 = *(const float*)r0 + edn;
        float x1 = *(const float*)r1 + edn;
        uint4 u0 = *(const uint4*)(r0 + 16 + q * 16);
        uint4 u1 = *(const uint4*)(r1 + 16 + q * 16);
        x0 = x0 > 0.f ? x0 : SLOPE * x0;
        x1 = x1 > 0.f ? x1 : SLOPE * x1;
        float w0 = __expf(x0);
        float w1 = (e + 1 < d) ? __expf(x1) : 0.f;
        den += w0 + w1;
        float f0[8] = {bf_lo(u0.x), bf_hi(u0.x), bf_lo(u0.y), bf_hi(u0.y),
                       bf_lo(u0.z), bf_hi(u0.z), bf_lo(u0.w), bf_hi(u0.w)};
        float f1[8] = {bf_lo(u1.x), bf_hi(u1.x), bf_lo(u1.y), bf_hi(u1.y),
                       bf_lo(u1.z), bf_hi(u1.z), bf_lo(u1.w), bf_hi(u1.w)};
        #pragma unroll
        for (int j = 0; j < 8; j++) acc[j] += w0 * f0[j] + w1 * f1[j];
    }
    float inv = 1.f / (den + 1e-10f);
    float o[8];
    #pragma unroll
    for (int j = 0; j < 8; j++) o[j] = acc[j] * inv;
    // softmax over 64 classes spread across the 8-lane group (xor 1,2,4 stays in-group)
    float mx = o[0];
    #pragma unroll
    for (int j = 1; j < 8; j++) mx = fmaxf(mx, o[j]);
    mx = fmaxf(mx, __shfl_xor(mx, 1));
    mx = fmaxf(mx, __shfl_xor(mx, 2));
    mx = fmaxf(mx, __shfl_xor(mx, 4));
    float e8[8], sm = 0.f;
    #pragma unroll
    for (int j = 0; j < 8; j++) { e8[j] = __expf(o[j] - mx); sm += e8[j]; }
    sm += __shfl_xor(sm, 1);
    sm += __shfl_xor(sm, 2);
    sm += __shfl_xor(sm, 4);
    float inv2 = 1.f / sm;
    float4* op = (float4*)(out + (size_t)n * 64 + q * 8);
    op[0] = make_float4(e8[0] * inv2, e8[1] * inv2, e8[2] * inv2, e8[3] * inv2);
    op[1] = make_float4(e8[4] * inv2, e8[5] * inv2, e8[6] * inv2, e8[7] * inv2);
}

// ---------------- launcher (4 dispatches, no memset) ----------------
extern "C" void kernel_launch(void* const* d_in, const int* in_sizes, int n_in,
                              void* d_out, int out_size, void* d_ws, size_t ws_size,
                              hipStream_t stream) {
    const float* X   = (const float*)d_in[0];
    const float* W1  = (const float*)d_in[1];
    const float* a1s = (const float*)d_in[2];
    const float* a1d = (const float*)d_in[3];
    const float* W2  = (const float*)d_in[4];
    const float* a2s = (const float*)d_in[5];
    const float* a2d = (const float*)d_in[6];
    const int*   src = (const int*)d_in[7];
    const int*   dst = (const int*)d_in[8];
    float* out = (float*)d_out;

    char* w = (char*)d_ws;
    size_t off = 0;
    auto alloc = [&](size_t bytes) {
        void* p = w + off;
        off += (bytes + 255) & ~(size_t)255;
        return p;
    };
    unsigned short* Bh  = (unsigned short*)alloc((size_t)C1 * F_IN * 2);
    unsigned short* Bl  = (unsigned short*)alloc((size_t)C1 * F_IN * 2);
    char*  rec1  = (char*)alloc((size_t)N_NODES * REC1);
    char*  rec2  = (char*)alloc((size_t)N_NODES * REC2);
    float* ed1   = (float*)alloc((size_t)N_NODES * 8 * 4);
    float* ed2   = (float*)alloc((size_t)N_NODES * 4);
    int*   deg   = (int*)alloc((size_t)N_NODES * DEGS * 4);
    int*   colPad= (int*)alloc((size_t)N_NODES * MAXDEG * 4);

    k_prep<<<NBLK_WT + NBLK_Z, 256, 0, stream>>>(W1, Bh, Bl, deg);
    // fused: 1/5 blocks = GEMM1+pack, 4/5 = histogram+scatter (1 edge/thread)
    k_gemm1f<<<NBLK_G1 * 5, 256, 0, stream>>>(X, Bh, Bl, a1s, a1d, rec1, ed1,
                                              src, dst, deg, colPad);
    k_agg1g2<<<(N_NODES + 31) / 32, 256, 0, stream>>>(rec1, ed1, deg, colPad,
                                                      W2, a2s, a2d, rec2, ed2);
    k_agg2<<<(N_NODES * 8 + 255) / 256, 256, 0, stream>>>(rec2, ed2, deg, colPad, out);
}

// Round 4
// 273.976 us; speedup vs baseline: 1.2604x; 1.0255x over previous
//
#include <hip/hip_runtime.h>
#include <math.h>

#define N_NODES 50000
#define N_EDGES 800000
#define F_IN    512
#define H1      8
#define F_HID   8
#define C1      64      // H1*F_HID
#define NLAB    64
#define SLOPE   0.2f
#define MAXDEG  64      // multinomial(800K,50K): mean 16, max ~35; 64 is safe

#define NBIN    98      // coarse node bins of 512 nodes (98*512 = 50176)
#define BINCAP  9216    // per-bin edge capacity: mean 8163, sigma ~90 -> +11 sigma
#define NBLK_WT  128    // 64*512/256 W1-split blocks
#define NBLK_E   196    // ceil(800000/4096) edge-binning blocks
#define NBLK_G1  782    // (50000+63)/64 gemm1 row-blocks

typedef __attribute__((ext_vector_type(8))) short short8;
typedef __attribute__((ext_vector_type(4))) float f32x4;

__device__ __forceinline__ float bf_lo(unsigned u) { return __uint_as_float(u << 16); }
__device__ __forceinline__ float bf_hi(unsigned u) { return __uint_as_float(u & 0xFFFF0000u); }
__device__ __forceinline__ unsigned short f2bf(float x) {
    unsigned bits = __float_as_uint(x);
    return (unsigned short)((bits + 0x7FFF + ((bits >> 16) & 1)) >> 16);   // RNE
}

// ------- prep: W1 bf16 split (blocks 0..127) + edge binning (128..323) -------
// Binning: per-block LDS histogram over 98 coarse bins (512 nodes each), ONE
// global atomic per (block,bin) to reserve space (19K atomics total vs 800K),
// then write (dst,src) records bin-contiguously (line-local 8B stores).
__global__ void k_prep(const float* __restrict__ W1, unsigned short* __restrict__ Bh,
                       unsigned short* __restrict__ Bl,
                       const int* __restrict__ src, const int* __restrict__ dst,
                       int2* __restrict__ ebuf, int* __restrict__ gctr) {
    int b = blockIdx.x;
    if (b < NBLK_WT) {
        int i = b * 256 + threadIdx.x;   // 0..32767
        int c = i >> 9, f = i & 511;
        float v = W1[(c >> 3) * (F_IN * F_HID) + f * F_HID + (c & 7)];
        unsigned bits = __float_as_uint(v);
        float r = v - __uint_as_float(bits & 0xFFFF0000u);
        Bh[i] = (unsigned short)(bits >> 16);
        Bl[i] = (unsigned short)(__float_as_uint(r) >> 16);
        return;
    }
    __shared__ int hist[NBIN];
    __shared__ int cur[NBIN];
    const int t = threadIdx.x;
    const int eb = b - NBLK_WT;          // 0..195, 4096 edges each
    if (t < NBIN) hist[t] = 0;
    __syncthreads();
    int4 dv[4], sv[4];
    const int e0 = eb * 4096 + t * 4;
    #pragma unroll
    for (int i = 0; i < 4; i++) {
        int e = e0 + i * 1024;
        if (e < N_EDGES) {
            dv[i] = *(const int4*)(dst + e);
            sv[i] = *(const int4*)(src + e);
            atomicAdd(&hist[dv[i].x >> 9], 1);
            atomicAdd(&hist[dv[i].y >> 9], 1);
            atomicAdd(&hist[dv[i].z >> 9], 1);
            atomicAdd(&hist[dv[i].w >> 9], 1);
        }
    }
    __syncthreads();
    if (t < NBIN) cur[t] = atomicAdd(&gctr[t], hist[t]);   // global base for this block
    __syncthreads();
    #pragma unroll
    for (int i = 0; i < 4; i++) {
        int e = e0 + i * 1024;
        if (e < N_EDGES) {
            int d, s, sl;
            d = dv[i].x; s = sv[i].x; sl = atomicAdd(&cur[d >> 9], 1);
            ebuf[(size_t)(d >> 9) * BINCAP + min(sl, BINCAP - 1)] = make_int2(d, s);
            d = dv[i].y; s = sv[i].y; sl = atomicAdd(&cur[d >> 9], 1);
            ebuf[(size_t)(d >> 9) * BINCAP + min(sl, BINCAP - 1)] = make_int2(d, s);
            d = dv[i].z; s = sv[i].z; sl = atomicAdd(&cur[d >> 9], 1);
            ebuf[(size_t)(d >> 9) * BINCAP + min(sl, BINCAP - 1)] = make_int2(d, s);
            d = dv[i].w; s = sv[i].w; sl = atomicAdd(&cur[d >> 9], 1);
            ebuf[(size_t)(d >> 9) * BINCAP + min(sl, BINCAP - 1)] = make_int2(d, s);
        }
    }
}

// ---------------- GEMM1 + es/ed pack, FUSED with per-bin CSR build ----------
// Blocks 0..97: bin b scans its ~8K binned edges; slots via LDS-only atomics;
// colPad writes confined to a 128KB region (L2-absorbed). deg written coalesced.
// Blocks 98..879: the GEMM path (row block = b-98). NO global atomics anywhere.
__launch_bounds__(256)
__global__ void k_gemm1f(const float* __restrict__ X, const unsigned short* __restrict__ Bh,
                         const unsigned short* __restrict__ Bl, const float* __restrict__ a_s,
                         const float* __restrict__ a_d, float* __restrict__ es1,
                         unsigned short* __restrict__ wh1, float* __restrict__ ed,
                         const int2* __restrict__ ebuf, const int* __restrict__ gctr,
                         int* __restrict__ deg, int* __restrict__ colPad) {
    __shared__ unsigned short sBh[64][136];
    __shared__ unsigned short sBl[64][136];

    const int b = blockIdx.x;
    const int t = threadIdx.x;
    if (b < NBIN) {                // ---- per-bin CSR build ----
        int* cnt = (int*)&sBh[0][0];          // 512 counters, reuse LDS
        const int lo = b << 9;
        const int cnum = min(gctr[b], BINCAP);
        for (int i = t; i < 512; i += 256) cnt[i] = 0;
        __syncthreads();
        const int2* eb2 = ebuf + (size_t)b * BINCAP;
        for (int i = t; i < cnum; i += 256) {
            int2 e = eb2[i];
            int sl = atomicAdd(&cnt[e.x - lo], 1);       // LDS atomic
            colPad[(e.x << 6) | min(sl, MAXDEG - 1)] = e.y;
        }
        __syncthreads();
        for (int i = t; i < 512; i += 256) {
            int n = lo + i;
            if (n < N_NODES) deg[n] = min(cnt[i], MAXDEG);
        }
        return;
    }

    const int lane = t & 63, w = t >> 6;
    const int r0 = (b - NBIN) * 64 + w * 16;
    const int m = lane & 15, quad = lane >> 4;
    int row = r0 + m; if (row >= N_NODES) row = N_NODES - 1;
    const float* xrow = X + (size_t)row * F_IN + quad * 8;

    const int sc = t >> 2;
    const int sp = t & 3;

    f32x4 acc[4] = {};
    float4 pxa[4], pxb[4];
    #pragma unroll
    for (int i = 0; i < 4; i++) {
        pxa[i] = *(const float4*)(xrow + i * 32);
        pxb[i] = *(const float4*)(xrow + i * 32 + 4);
    }

    for (int chunk = 0; chunk < 4; chunk++) {
        const int k0 = chunk * 128;
        if (chunk) __syncthreads();
        #pragma unroll
        for (int i = 0; i < 4; i++) {
            *(short8*)(&sBh[sc][sp * 32 + i * 8]) =
                *(const short8*)(Bh + sc * F_IN + k0 + sp * 32 + i * 8);
            *(short8*)(&sBl[sc][sp * 32 + i * 8]) =
                *(const short8*)(Bl + sc * F_IN + k0 + sp * 32 + i * 8);
        }
        __syncthreads();
        #pragma unroll
        for (int i = 0; i < 4; i++) {
            float xs[8] = {pxa[i].x, pxa[i].y, pxa[i].z, pxa[i].w,
                           pxb[i].x, pxb[i].y, pxb[i].z, pxb[i].w};
            if (chunk < 3) {
                const int ktn = k0 + 128 + i * 32;
                pxa[i] = *(const float4*)(xrow + ktn);
                pxb[i] = *(const float4*)(xrow + ktn + 4);
            }
            short8 ah, al;
            #pragma unroll
            for (int j = 0; j < 8; j++) {
                unsigned bits = __float_as_uint(xs[j]);
                float rr = xs[j] - __uint_as_float(bits & 0xFFFF0000u);
                ah[j] = (short)(bits >> 16);
                al[j] = (short)(__float_as_uint(rr) >> 16);
            }
            #pragma unroll
            for (int s = 0; s < 4; s++) {
                short8 bh = *(const short8*)(&sBh[s * 16 + m][i * 32 + quad * 8]);
                short8 bl = *(const short8*)(&sBl[s * 16 + m][i * 32 + quad * 8]);
                acc[s] = __builtin_amdgcn_mfma_f32_16x16x32_bf16(al, bh, acc[s], 0, 0, 0);
                acc[s] = __builtin_amdgcn_mfma_f32_16x16x32_bf16(ah, bl, acc[s], 0, 0, 0);
                acc[s] = __builtin_amdgcn_mfma_f32_16x16x32_bf16(ah, bh, acc[s], 0, 0, 0);
            }
        }
    }
    __syncthreads();
    unsigned short* sWh = &sBh[0][0] + w * 1024;
    #pragma unroll
    for (int s = 0; s < 4; s++)
        #pragma unroll
        for (int reg = 0; reg < 4; reg++)
            sWh[(quad * 4 + reg) * 64 + s * 16 + m] = f2bf(acc[s][reg]);
    __syncthreads();
    const int rr = lane & 15, p = lane >> 4;
    const int n = r0 + rr;
    if (n >= N_NODES) return;
    float es2v[2], edv[2];
    #pragma unroll
    for (int hh = 0; hh < 2; hh++) {
        int h = 2 * p + hh;
        float s = 0.f, dsum = 0.f;
        #pragma unroll
        for (int j = 0; j < 8; j++) {
            float v = __uint_as_float((unsigned)sWh[rr * 64 + h * 8 + j] << 16);
            s += v * a_s[h * 8 + j];
            dsum += v * a_d[h * 8 + j];
        }
        es2v[hh] = s; edv[hh] = dsum;
    }
    *(float2*)(es1 + n * 8 + 2 * p) = make_float2(es2v[0], es2v[1]);
    *(short8*)(wh1 + (size_t)n * 64 + p * 16)     = *(const short8*)(sWh + rr * 64 + p * 16);
    *(short8*)(wh1 + (size_t)n * 64 + p * 16 + 8) = *(const short8*)(sWh + rr * 64 + p * 16 + 8);
    *(float2*)(ed + n * 8 + 2 * p) = make_float2(edv[0], edv[1]);
}

// -------- FUSED layer-1 aggregation (8 lanes/node) + GEMM2 (K=64) --------
// Agg: preload whole colPad row (2x int4/lane), shfl-broadcast slot ids,
// issue all gathers as INDEPENDENT loads (MLP, no col->rec serial chain).
__launch_bounds__(256)
__global__ void k_agg1g2(const float* __restrict__ es1, const unsigned short* __restrict__ wh1,
                         const float* __restrict__ ed,
                         const int* __restrict__ deg, const int* __restrict__ colPad,
                         const float* __restrict__ W2, const float* __restrict__ a2s,
                         const float* __restrict__ a2d,
                         float* __restrict__ es2, unsigned short* __restrict__ wh2,
                         float* __restrict__ ed2) {
    __shared__ float Ws[64 * 64];    // 16KB
    __shared__ float hs[32][64];     // 8KB
    const int t = threadIdx.x;
    #pragma unroll
    for (int i = 0; i < 4; i++) {
        int flat = i * 256 + t;
        *(float4*)(Ws + flat * 4) = *(const float4*)(W2 + flat * 4);
    }
    const int n0 = blockIdx.x * 32;
    const int n = n0 + (t >> 3), q = t & 7;
    const int gb = (t & 63) & 56;    // group base lane within wave

    float o[8] = {};
    if (n < N_NODES) {
        const int d = deg[n];
        const int base = n << 6;
        int4 c0 = *(const int4*)(colPad + base + q * 4);        // slots 4q..4q+3
        int4 c1 = *(const int4*)(colPad + base + 32 + q * 4);   // slots 32+4q..
        float edq = ed[n * 8 + q];
        float den = 0.f;
        float acc[8] = {};
        #pragma unroll
        for (int comp = 0; comp < 4; comp++) {
            int m0 = (comp == 0) ? c0.x : (comp == 1) ? c0.y : (comp == 2) ? c0.z : c0.w;
            int m1 = (comp == 0) ? c1.x : (comp == 1) ? c1.y : (comp == 2) ? c1.z : c1.w;
            #pragma unroll
            for (int srcl = 0; srcl < 8; srcl++) {
                int sv0 = __shfl(m0, gb + srcl);
                int sv1 = __shfl(m1, gb + srcl);
                int i0 = srcl * 4 + comp;
                if (i0 < d) {
                    float x = es1[sv0 * 8 + q] + edq;
                    uint4 u = *(const uint4*)(wh1 + (size_t)sv0 * 64 + q * 8);
                    x = x > 0.f ? x : SLOPE * x;
                    float wg = __expf(x);
                    den += wg;
                    acc[0] += wg * bf_lo(u.x); acc[1] += wg * bf_hi(u.x);
                    acc[2] += wg * bf_lo(u.y); acc[3] += wg * bf_hi(u.y);
                    acc[4] += wg * bf_lo(u.z); acc[5] += wg * bf_hi(u.z);
                    acc[6] += wg * bf_lo(u.w); acc[7] += wg * bf_hi(u.w);
                }
                if (i0 + 32 < d) {
                    float x = es1[sv1 * 8 + q] + edq;
                    uint4 u = *(const uint4*)(wh1 + (size_t)sv1 * 64 + q * 8);
                    x = x > 0.f ? x : SLOPE * x;
                    float wg = __expf(x);
                    den += wg;
                    acc[0] += wg * bf_lo(u.x); acc[1] += wg * bf_hi(u.x);
                    acc[2] += wg * bf_lo(u.y); acc[3] += wg * bf_hi(u.y);
                    acc[4] += wg * bf_lo(u.z); acc[5] += wg * bf_hi(u.z);
                    acc[6] += wg * bf_lo(u.w); acc[7] += wg * bf_hi(u.w);
                }
            }
        }
        float inv = 1.f / (den + 1e-10f);
        #pragma unroll
        for (int j = 0; j < 8; j++) {
            float v = acc[j] * inv;
            o[j] = v > 0.f ? v : expm1f(v);   // fused ELU
        }
    }
    float4* hp = (float4*)(&hs[t >> 3][q * 8]);
    hp[0] = make_float4(o[0], o[1], o[2], o[3]);
    hp[1] = make_float4(o[4], o[5], o[6], o[7]);
    __syncthreads();

    // ---- GEMM2 phase: wave wv handles 8 nodes, lane = output class ----
    const int wv = t >> 6, lane = t & 63;
    float as = a2s[lane], ad = a2d[lane];
    #pragma unroll
    for (int j = 0; j < 8; j++) {
        int nl = wv * 8 + j;
        int nn = n0 + nl;
        if (nn >= N_NODES) break;
        float acc = 0.f;
        #pragma unroll
        for (int k = 0; k < 64; k++) acc += hs[nl][k] * Ws[k * 64 + lane];
        wh2[(size_t)nn * 64 + lane] = f2bf(acc);
        float s = acc * as;
        float dd = acc * ad;
        #pragma unroll
        for (int off = 1; off < 64; off <<= 1) {
            s += __shfl_xor(s, off);
            dd += __shfl_xor(dd, off);
        }
        if (lane == 0) { es2[nn] = s; ed2[nn] = dd; }
    }
}

// ---------------- layer-2 aggregation (same MLP structure) + final softmax ----------
__launch_bounds__(256)
__global__ void k_agg2(const float* __restrict__ es2, const unsigned short* __restrict__ wh2,
                       const float* __restrict__ ed2,
                       const int* __restrict__ deg, const int* __restrict__ colPad,
                       float* __restrict__ out) {
    int tid = blockIdx.x * 256 + threadIdx.x;
    int n = tid >> 3, q = tid & 7;
    if (n >= N_NODES) return;
    const int t = threadIdx.x;
    const int gb = (t & 63) & 56;
    const int d = deg[n];
    const int base = n << 6;
    int4 c0 = *(const int4*)(colPad + base + q * 4);
    int4 c1 = *(const int4*)(colPad + base + 32 + q * 4);
    float edn = ed2[n];

    float den = 0.f;
    float acc[8] = {};
    #pragma unroll
    for (int comp = 0; comp < 4; comp++) {
        int m0 = (comp == 0) ? c0.x : (comp == 1) ? c0.y : (comp == 2) ? c0.z : c0.w;
        int m1 = (comp == 0) ? c1.x : (comp == 1) ? c1.y : (comp == 2) ? c1.z : c1.w;
        #pragma unroll
        for (int srcl = 0; srcl < 8; srcl++) {
            int sv0 = __shfl(m0, gb + srcl);
            int sv1 = __shfl(m1, gb + srcl);
            int i0 = srcl * 4 + comp;
            if (i0 < d) {
                float x = es2[sv0] + edn;
                uint4 u = *(const uint4*)(wh2 + (size_t)sv0 * 64 + q * 8);
                x = x > 0.f ? x : SLOPE * x;
                float wg = __expf(x);
                den += wg;
                acc[0] += wg * bf_lo(u.x); acc[1] += wg * bf_hi(u.x);
                acc[2] += wg * bf_lo(u.y); acc[3] += wg * bf_hi(u.y);
                acc[4] += wg * bf_lo(u.z); acc[5] += wg * bf_hi(u.z);
                acc[6] += wg * bf_lo(u.w); acc[7] += wg * bf_hi(u.w);
            }
            if (i0 + 32 < d) {
                float x = es2[sv1] + edn;
                uint4 u = *(const uint4*)(wh2 + (size_t)sv1 * 64 + q * 8);
                x = x > 0.f ? x : SLOPE * x;
                float wg = __expf(x);
                den += wg;
                acc[0] += wg * bf_lo(u.x); acc[1] += wg * bf_hi(u.x);
                acc[2] += wg * bf_lo(u.y); acc[3] += wg * bf_hi(u.y);
                acc[4] += wg * bf_lo(u.z); acc[5] += wg * bf_hi(u.z);
                acc[6] += wg * bf_lo(u.w); acc[7] += wg * bf_hi(u.w);
            }
        }
    }
    float inv = 1.f / (den + 1e-10f);
    float o[8];
    #pragma unroll
    for (int j = 0; j < 8; j++) o[j] = acc[j] * inv;
    // softmax over 64 classes spread across the 8-lane group (xor 1,2,4 stays in-group)
    float mx = o[0];
    #pragma unroll
    for (int j = 1; j < 8; j++) mx = fmaxf(mx, o[j]);
    mx = fmaxf(mx, __shfl_xor(mx, 1));
    mx = fmaxf(mx, __shfl_xor(mx, 2));
    mx = fmaxf(mx, __shfl_xor(mx, 4));
    float e8[8], sm = 0.f;
    #pragma unroll
    for (int j = 0; j < 8; j++) { e8[j] = __expf(o[j] - mx); sm += e8[j]; }
    sm += __shfl_xor(sm, 1);
    sm += __shfl_xor(sm, 2);
    sm += __shfl_xor(sm, 4);
    float inv2 = 1.f / sm;
    float4* op = (float4*)(out + (size_t)n * 64 + q * 8);
    op[0] = make_float4(e8[0] * inv2, e8[1] * inv2, e8[2] * inv2, e8[3] * inv2);
    op[1] = make_float4(e8[4] * inv2, e8[5] * inv2, e8[6] * inv2, e8[7] * inv2);
}

// ---------------- launcher (4 dispatches + tiny memset) ----------------
extern "C" void kernel_launch(void* const* d_in, const int* in_sizes, int n_in,
                              void* d_out, int out_size, void* d_ws, size_t ws_size,
                              hipStream_t stream) {
    const float* X   = (const float*)d_in[0];
    const float* W1  = (const float*)d_in[1];
    const float* a1s = (const float*)d_in[2];
    const float* a1d = (const float*)d_in[3];
    const float* W2  = (const float*)d_in[4];
    const float* a2s = (const float*)d_in[5];
    const float* a2d = (const float*)d_in[6];
    const int*   src = (const int*)d_in[7];
    const int*   dst = (const int*)d_in[8];
    float* out = (float*)d_out;

    char* w = (char*)d_ws;
    size_t off = 0;
    auto alloc = [&](size_t bytes) {
        void* p = w + off;
        off += (bytes + 255) & ~(size_t)255;
        return p;
    };
    unsigned short* Bh   = (unsigned short*)alloc((size_t)C1 * F_IN * 2);
    unsigned short* Bl   = (unsigned short*)alloc((size_t)C1 * F_IN * 2);
    float*          es1  = (float*)alloc((size_t)N_NODES * 8 * 4);
    unsigned short* wh1  = (unsigned short*)alloc((size_t)N_NODES * 64 * 2);
    float*          es2  = (float*)alloc((size_t)N_NODES * 4);
    unsigned short* wh2  = (unsigned short*)alloc((size_t)N_NODES * 64 * 2);
    float*          ed1  = (float*)alloc((size_t)N_NODES * 8 * 4);
    float*          ed2  = (float*)alloc((size_t)N_NODES * 4);
    int*            deg  = (int*)alloc((size_t)N_NODES * 4);
    int*            colPad = (int*)alloc((size_t)N_NODES * MAXDEG * 4);
    int2*           ebuf = (int2*)alloc((size_t)NBIN * BINCAP * 8);
    int*            gctr = (int*)alloc((size_t)NBIN * 4);

    hipMemsetAsync(gctr, 0, NBIN * 4, stream);

    k_prep<<<NBLK_WT + NBLK_E, 256, 0, stream>>>(W1, Bh, Bl, src, dst, ebuf, gctr);
    k_gemm1f<<<NBIN + NBLK_G1, 256, 0, stream>>>(X, Bh, Bl, a1s, a1d, es1, wh1, ed1,
                                                 ebuf, gctr, deg, colPad);
    k_agg1g2<<<(N_NODES + 31) / 32, 256, 0, stream>>>(es1, wh1, ed1, deg, colPad,
                                                      W2, a2s, a2d, es2, wh2, ed2);
    k_agg2<<<(N_NODES * 8 + 255) / 256, 256, 0, stream>>>(es2, wh2, ed2, deg, colPad, out);
}

// Round 5
// 269.598 us; speedup vs baseline: 1.2808x; 1.0162x over previous
//
#include <hip/hip_runtime.h>
#include <math.h>

#define N_NODES 50000
#define N_EDGES 800000
#define F_IN    512
#define H1      8
#define F_HID   8
#define C1      64      // H1*F_HID
#define NLAB    64
#define SLOPE   0.2f
#define MAXDEG  64      // multinomial(800K,50K): mean 16, max ~35; 64 is safe

#define NBIN    98      // coarse node bins of 512 nodes (98*512 = 50176)
#define BINCAP  9216    // per-bin edge capacity: mean 8163, sigma ~90 -> +11 sigma
#define NBLK_WT  128    // 64*512/256 W1-split blocks
#define NBLK_E   196    // ceil(800000/4096) edge-binning blocks
#define NBLK_G1  782    // (50000+63)/64 gemm1 row-blocks

typedef __attribute__((ext_vector_type(8))) short short8;
typedef __attribute__((ext_vector_type(4))) float f32x4;

__device__ __forceinline__ float bf_lo(unsigned u) { return __uint_as_float(u << 16); }
__device__ __forceinline__ float bf_hi(unsigned u) { return __uint_as_float(u & 0xFFFF0000u); }
__device__ __forceinline__ unsigned short f2bf(float x) {
    unsigned bits = __float_as_uint(x);
    return (unsigned short)((bits + 0x7FFF + ((bits >> 16) & 1)) >> 16);   // RNE
}

// ---------------- prep: W1 bf16 split only (tiny) ----------------
__global__ void k_prep(const float* __restrict__ W1, unsigned short* __restrict__ Bh,
                       unsigned short* __restrict__ Bl) {
    int i = blockIdx.x * 256 + threadIdx.x;   // 0..32767
    int c = i >> 9, f = i & 511;
    float v = W1[(c >> 3) * (F_IN * F_HID) + f * F_HID + (c & 7)];
    unsigned bits = __float_as_uint(v);
    float r = v - __uint_as_float(bits & 0xFFFF0000u);
    Bh[i] = (unsigned short)(bits >> 16);
    Bl[i] = (unsigned short)(__float_as_uint(r) >> 16);
}

// -------- GEMM1 + es/ed pack, FUSED with edge BINNING (independent work) --------
// Blocks 0..195: edge binning (per-block LDS hist over 98 bins, ONE global
// atomic per (block,bin), bin-contiguous 8B writes) — hidden under the GEMM.
// Blocks 196..977: GEMM row-block = b-196. __launch_bounds__(256,4): LDS caps
// us at 4 blocks/CU anyway; ask for 4 waves/SIMD so the compiler gets a
// 128-VGPR budget and can keep the X-prefetch pipeline in registers
// (at the default bounds it allocated 56 VGPRs and serialized the loads).
__launch_bounds__(256, 4)
__global__ void k_gemm1b(const float* __restrict__ X, const unsigned short* __restrict__ Bh,
                         const unsigned short* __restrict__ Bl, const float* __restrict__ a_s,
                         const float* __restrict__ a_d, float* __restrict__ es1,
                         unsigned short* __restrict__ wh1, float* __restrict__ ed,
                         const int* __restrict__ src, const int* __restrict__ dst,
                         int2* __restrict__ ebuf, int* __restrict__ gctr) {
    __shared__ unsigned short sBh[64][136];
    __shared__ unsigned short sBl[64][136];

    const int b = blockIdx.x;
    const int t = threadIdx.x;
    if (b < NBLK_E) {              // ---- edge binning path ----
        int* hist = (int*)&sBh[0][0];
        int* cur  = hist + 128;
        if (t < NBIN) hist[t] = 0;
        __syncthreads();
        int4 dv[4], sv[4];
        const int e0 = b * 4096 + t * 4;
        #pragma unroll
        for (int i = 0; i < 4; i++) {
            int e = e0 + i * 1024;
            if (e < N_EDGES) {
                dv[i] = *(const int4*)(dst + e);
                sv[i] = *(const int4*)(src + e);
                atomicAdd(&hist[dv[i].x >> 9], 1);
                atomicAdd(&hist[dv[i].y >> 9], 1);
                atomicAdd(&hist[dv[i].z >> 9], 1);
                atomicAdd(&hist[dv[i].w >> 9], 1);
            }
        }
        __syncthreads();
        if (t < NBIN) cur[t] = atomicAdd(&gctr[t], hist[t]);
        __syncthreads();
        #pragma unroll
        for (int i = 0; i < 4; i++) {
            int e = e0 + i * 1024;
            if (e < N_EDGES) {
                int d, s, sl;
                d = dv[i].x; s = sv[i].x; sl = atomicAdd(&cur[d >> 9], 1);
                ebuf[(size_t)(d >> 9) * BINCAP + min(sl, BINCAP - 1)] = make_int2(d, s);
                d = dv[i].y; s = sv[i].y; sl = atomicAdd(&cur[d >> 9], 1);
                ebuf[(size_t)(d >> 9) * BINCAP + min(sl, BINCAP - 1)] = make_int2(d, s);
                d = dv[i].z; s = sv[i].z; sl = atomicAdd(&cur[d >> 9], 1);
                ebuf[(size_t)(d >> 9) * BINCAP + min(sl, BINCAP - 1)] = make_int2(d, s);
                d = dv[i].w; s = sv[i].w; sl = atomicAdd(&cur[d >> 9], 1);
                ebuf[(size_t)(d >> 9) * BINCAP + min(sl, BINCAP - 1)] = make_int2(d, s);
            }
        }
        return;
    }

    const int lane = t & 63, w = t >> 6;
    const int r0 = (b - NBLK_E) * 64 + w * 16;
    const int m = lane & 15, quad = lane >> 4;
    int row = r0 + m; if (row >= N_NODES) row = N_NODES - 1;
    const float* xrow = X + (size_t)row * F_IN + quad * 8;

    const int sc = t >> 2;
    const int sp = t & 3;

    f32x4 acc[4] = {};
    float4 pxa[4], pxb[4];
    #pragma unroll
    for (int i = 0; i < 4; i++) {
        pxa[i] = *(const float4*)(xrow + i * 32);
        pxb[i] = *(const float4*)(xrow + i * 32 + 4);
    }

    for (int chunk = 0; chunk < 4; chunk++) {
        const int k0 = chunk * 128;
        if (chunk) __syncthreads();
        #pragma unroll
        for (int i = 0; i < 4; i++) {
            *(short8*)(&sBh[sc][sp * 32 + i * 8]) =
                *(const short8*)(Bh + sc * F_IN + k0 + sp * 32 + i * 8);
            *(short8*)(&sBl[sc][sp * 32 + i * 8]) =
                *(const short8*)(Bl + sc * F_IN + k0 + sp * 32 + i * 8);
        }
        __syncthreads();
        #pragma unroll
        for (int i = 0; i < 4; i++) {
            float xs[8] = {pxa[i].x, pxa[i].y, pxa[i].z, pxa[i].w,
                           pxb[i].x, pxb[i].y, pxb[i].z, pxb[i].w};
            if (chunk < 3) {
                const int ktn = k0 + 128 + i * 32;
                pxa[i] = *(const float4*)(xrow + ktn);
                pxb[i] = *(const float4*)(xrow + ktn + 4);
            }
            short8 ah, al;
            #pragma unroll
            for (int j = 0; j < 8; j++) {
                unsigned bits = __float_as_uint(xs[j]);
                float rr = xs[j] - __uint_as_float(bits & 0xFFFF0000u);
                ah[j] = (short)(bits >> 16);
                al[j] = (short)(__float_as_uint(rr) >> 16);
            }
            #pragma unroll
            for (int s = 0; s < 4; s++) {
                short8 bh = *(const short8*)(&sBh[s * 16 + m][i * 32 + quad * 8]);
                short8 bl = *(const short8*)(&sBl[s * 16 + m][i * 32 + quad * 8]);
                acc[s] = __builtin_amdgcn_mfma_f32_16x16x32_bf16(al, bh, acc[s], 0, 0, 0);
                acc[s] = __builtin_amdgcn_mfma_f32_16x16x32_bf16(ah, bl, acc[s], 0, 0, 0);
                acc[s] = __builtin_amdgcn_mfma_f32_16x16x32_bf16(ah, bh, acc[s], 0, 0, 0);
            }
        }
    }
    __syncthreads();
    unsigned short* sWh = &sBh[0][0] + w * 1024;
    #pragma unroll
    for (int s = 0; s < 4; s++)
        #pragma unroll
        for (int reg = 0; reg < 4; reg++)
            sWh[(quad * 4 + reg) * 64 + s * 16 + m] = f2bf(acc[s][reg]);
    __syncthreads();
    const int rr = lane & 15, p = lane >> 4;
    const int n = r0 + rr;
    if (n >= N_NODES) return;
    float es2v[2], edv[2];
    #pragma unroll
    for (int hh = 0; hh < 2; hh++) {
        int h = 2 * p + hh;
        float s = 0.f, dsum = 0.f;
        #pragma unroll
        for (int j = 0; j < 8; j++) {
            float v = __uint_as_float((unsigned)sWh[rr * 64 + h * 8 + j] << 16);
            s += v * a_s[h * 8 + j];
            dsum += v * a_d[h * 8 + j];
        }
        es2v[hh] = s; edv[hh] = dsum;
    }
    *(float2*)(es1 + n * 8 + 2 * p) = make_float2(es2v[0], es2v[1]);
    *(short8*)(wh1 + (size_t)n * 64 + p * 16)     = *(const short8*)(sWh + rr * 64 + p * 16);
    *(short8*)(wh1 + (size_t)n * 64 + p * 16 + 8) = *(const short8*)(sWh + rr * 64 + p * 16 + 8);
    *(float2*)(ed + n * 8 + 2 * p) = make_float2(edv[0], edv[1]);
}

// ---------------- per-bin CSR build (LDS-only slot atomics) ----------------
__global__ void k_csr(const int2* __restrict__ ebuf, const int* __restrict__ gctr,
                      int* __restrict__ deg, int* __restrict__ colPad) {
    __shared__ int cnt[512];
    const int b = blockIdx.x, t = threadIdx.x;
    const int lo = b << 9;
    const int cnum = min(gctr[b], BINCAP);
    for (int i = t; i < 512; i += 256) cnt[i] = 0;
    __syncthreads();
    const int2* eb2 = ebuf + (size_t)b * BINCAP;
    for (int i = t; i < cnum; i += 256) {
        int2 e = eb2[i];
        int sl = atomicAdd(&cnt[e.x - lo], 1);       // LDS atomic
        colPad[(e.x << 6) | min(sl, MAXDEG - 1)] = e.y;
    }
    __syncthreads();
    for (int i = t; i < 512; i += 256) {
        int n = lo + i;
        if (n < N_NODES) deg[n] = min(cnt[i], MAXDEG);
    }
}

// -------- FUSED layer-1 aggregation (8 lanes/node) + GEMM2 (K=64) --------
// Agg: preload whole colPad row (2x int4/lane), shfl-broadcast slot ids,
// issue all gathers as INDEPENDENT loads (MLP, no col->rec serial chain).
__launch_bounds__(256)
__global__ void k_agg1g2(const float* __restrict__ es1, const unsigned short* __restrict__ wh1,
                         const float* __restrict__ ed,
                         const int* __restrict__ deg, const int* __restrict__ colPad,
                         const float* __restrict__ W2, const float* __restrict__ a2s,
                         const float* __restrict__ a2d,
                         float* __restrict__ es2, unsigned short* __restrict__ wh2,
                         float* __restrict__ ed2) {
    __shared__ float Ws[64 * 64];    // 16KB
    __shared__ float hs[32][64];     // 8KB
    const int t = threadIdx.x;
    #pragma unroll
    for (int i = 0; i < 4; i++) {
        int flat = i * 256 + t;
        *(float4*)(Ws + flat * 4) = *(const float4*)(W2 + flat * 4);
    }
    const int n0 = blockIdx.x * 32;
    const int n = n0 + (t >> 3), q = t & 7;
    const int gb = (t & 63) & 56;    // group base lane within wave

    float o[8] = {};
    if (n < N_NODES) {
        const int d = deg[n];
        const int base = n << 6;
        int4 c0 = *(const int4*)(colPad + base + q * 4);        // slots 4q..4q+3
        int4 c1 = *(const int4*)(colPad + base + 32 + q * 4);   // slots 32+4q..
        float edq = ed[n * 8 + q];
        float den = 0.f;
        float acc[8] = {};
        #pragma unroll
        for (int comp = 0; comp < 4; comp++) {
            int m0 = (comp == 0) ? c0.x : (comp == 1) ? c0.y : (comp == 2) ? c0.z : c0.w;
            int m1 = (comp == 0) ? c1.x : (comp == 1) ? c1.y : (comp == 2) ? c1.z : c1.w;
            #pragma unroll
            for (int srcl = 0; srcl < 8; srcl++) {
                int sv0 = __shfl(m0, gb + srcl);
                int sv1 = __shfl(m1, gb + srcl);
                int i0 = srcl * 4 + comp;
                if (i0 < d) {
                    float x = es1[sv0 * 8 + q] + edq;
                    uint4 u = *(const uint4*)(wh1 + (size_t)sv0 * 64 + q * 8);
                    x = x > 0.f ? x : SLOPE * x;
                    float wg = __expf(x);
                    den += wg;
                    acc[0] += wg * bf_lo(u.x); acc[1] += wg * bf_hi(u.x);
                    acc[2] += wg * bf_lo(u.y); acc[3] += wg * bf_hi(u.y);
                    acc[4] += wg * bf_lo(u.z); acc[5] += wg * bf_hi(u.z);
                    acc[6] += wg * bf_lo(u.w); acc[7] += wg * bf_hi(u.w);
                }
                if (i0 + 32 < d) {
                    float x = es1[sv1 * 8 + q] + edq;
                    uint4 u = *(const uint4*)(wh1 + (size_t)sv1 * 64 + q * 8);
                    x = x > 0.f ? x : SLOPE * x;
                    float wg = __expf(x);
                    den += wg;
                    acc[0] += wg * bf_lo(u.x); acc[1] += wg * bf_hi(u.x);
                    acc[2] += wg * bf_lo(u.y); acc[3] += wg * bf_hi(u.y);
                    acc[4] += wg * bf_lo(u.z); acc[5] += wg * bf_hi(u.z);
                    acc[6] += wg * bf_lo(u.w); acc[7] += wg * bf_hi(u.w);
                }
            }
        }
        float inv = 1.f / (den + 1e-10f);
        #pragma unroll
        for (int j = 0; j < 8; j++) {
            float v = acc[j] * inv;
            o[j] = v > 0.f ? v : expm1f(v);   // fused ELU
        }
    }
    float4* hp = (float4*)(&hs[t >> 3][q * 8]);
    hp[0] = make_float4(o[0], o[1], o[2], o[3]);
    hp[1] = make_float4(o[4], o[5], o[6], o[7]);
    __syncthreads();

    // ---- GEMM2 phase: wave wv handles 8 nodes, lane = output class ----
    const int wv = t >> 6, lane = t & 63;
    float as = a2s[lane], ad = a2d[lane];
    #pragma unroll
    for (int j = 0; j < 8; j++) {
        int nl = wv * 8 + j;
        int nn = n0 + nl;
        if (nn >= N_NODES) break;
        float acc = 0.f;
        #pragma unroll
        for (int k = 0; k < 64; k++) acc += hs[nl][k] * Ws[k * 64 + lane];
        wh2[(size_t)nn * 64 + lane] = f2bf(acc);
        float s = acc * as;
        float dd = acc * ad;
        #pragma unroll
        for (int off = 1; off < 64; off <<= 1) {
            s += __shfl_xor(s, off);
            dd += __shfl_xor(dd, off);
        }
        if (lane == 0) { es2[nn] = s; ed2[nn] = dd; }
    }
}

// ---------------- layer-2 aggregation (same MLP structure) + final softmax ----------
__launch_bounds__(256)
__global__ void k_agg2(const float* __restrict__ es2, const unsigned short* __restrict__ wh2,
                       const float* __restrict__ ed2,
                       const int* __restrict__ deg, const int* __restrict__ colPad,
                       float* __restrict__ out) {
    int tid = blockIdx.x * 256 + threadIdx.x;
    int n = tid >> 3, q = tid & 7;
    if (n >= N_NODES) return;
    const int t = threadIdx.x;
    const int gb = (t & 63) & 56;
    const int d = deg[n];
    const int base = n << 6;
    int4 c0 = *(const int4*)(colPad + base + q * 4);
    int4 c1 = *(const int4*)(colPad + base + 32 + q * 4);
    float edn = ed2[n];

    float den = 0.f;
    float acc[8] = {};
    #pragma unroll
    for (int comp = 0; comp < 4; comp++) {
        int m0 = (comp == 0) ? c0.x : (comp == 1) ? c0.y : (comp == 2) ? c0.z : c0.w;
        int m1 = (comp == 0) ? c1.x : (comp == 1) ? c1.y : (comp == 2) ? c1.z : c1.w;
        #pragma unroll
        for (int srcl = 0; srcl < 8; srcl++) {
            int sv0 = __shfl(m0, gb + srcl);
            int sv1 = __shfl(m1, gb + srcl);
            int i0 = srcl * 4 + comp;
            if (i0 < d) {
                float x = es2[sv0] + edn;
                uint4 u = *(const uint4*)(wh2 + (size_t)sv0 * 64 + q * 8);
                x = x > 0.f ? x : SLOPE * x;
                float wg = __expf(x);
                den += wg;
                acc[0] += wg * bf_lo(u.x); acc[1] += wg * bf_hi(u.x);
                acc[2] += wg * bf_lo(u.y); acc[3] += wg * bf_hi(u.y);
                acc[4] += wg * bf_lo(u.z); acc[5] += wg * bf_hi(u.z);
                acc[6] += wg * bf_lo(u.w); acc[7] += wg * bf_hi(u.w);
            }
            if (i0 + 32 < d) {
                float x = es2[sv1] + edn;
                uint4 u = *(const uint4*)(wh2 + (size_t)sv1 * 64 + q * 8);
                x = x > 0.f ? x : SLOPE * x;
                float wg = __expf(x);
                den += wg;
                acc[0] += wg * bf_lo(u.x); acc[1] += wg * bf_hi(u.x);
                acc[2] += wg * bf_lo(u.y); acc[3] += wg * bf_hi(u.y);
                acc[4] += wg * bf_lo(u.z); acc[5] += wg * bf_hi(u.z);
                acc[6] += wg * bf_lo(u.w); acc[7] += wg * bf_hi(u.w);
            }
        }
    }
    float inv = 1.f / (den + 1e-10f);
    float o[8];
    #pragma unroll
    for (int j = 0; j < 8; j++) o[j] = acc[j] * inv;
    // softmax over 64 classes spread across the 8-lane group (xor 1,2,4 stays in-group)
    float mx = o[0];
    #pragma unroll
    for (int j = 1; j < 8; j++) mx = fmaxf(mx, o[j]);
    mx = fmaxf(mx, __shfl_xor(mx, 1));
    mx = fmaxf(mx, __shfl_xor(mx, 2));
    mx = fmaxf(mx, __shfl_xor(mx, 4));
    float e8[8], sm = 0.f;
    #pragma unroll
    for (int j = 0; j < 8; j++) { e8[j] = __expf(o[j] - mx); sm += e8[j]; }
    sm += __shfl_xor(sm, 1);
    sm += __shfl_xor(sm, 2);
    sm += __shfl_xor(sm, 4);
    float inv2 = 1.f / sm;
    float4* op = (float4*)(out + (size_t)n * 64 + q * 8);
    op[0] = make_float4(e8[0] * inv2, e8[1] * inv2, e8[2] * inv2, e8[3] * inv2);
    op[1] = make_float4(e8[4] * inv2, e8[5] * inv2, e8[6] * inv2, e8[7] * inv2);
}

// ---------------- launcher (5 dispatches + tiny memset) ----------------
extern "C" void kernel_launch(void* const* d_in, const int* in_sizes, int n_in,
                              void* d_out, int out_size, void* d_ws, size_t ws_size,
                              hipStream_t stream) {
    const float* X   = (const float*)d_in[0];
    const float* W1  = (const float*)d_in[1];
    const float* a1s = (const float*)d_in[2];
    const float* a1d = (const float*)d_in[3];
    const float* W2  = (const float*)d_in[4];
    const float* a2s = (const float*)d_in[5];
    const float* a2d = (const float*)d_in[6];
    const int*   src = (const int*)d_in[7];
    const int*   dst = (const int*)d_in[8];
    float* out = (float*)d_out;

    char* w = (char*)d_ws;
    size_t off = 0;
    auto alloc = [&](size_t bytes) {
        void* p = w + off;
        off += (bytes + 255) & ~(size_t)255;
        return p;
    };
    unsigned short* Bh   = (unsigned short*)alloc((size_t)C1 * F_IN * 2);
    unsigned short* Bl   = (unsigned short*)alloc((size_t)C1 * F_IN * 2);
    float*          es1  = (float*)alloc((size_t)N_NODES * 8 * 4);
    unsigned short* wh1  = (unsigned short*)alloc((size_t)N_NODES * 64 * 2);
    float*          es2  = (float*)alloc((size_t)N_NODES * 4);
    unsigned short* wh2  = (unsigned short*)alloc((size_t)N_NODES * 64 * 2);
    float*          ed1  = (float*)alloc((size_t)N_NODES * 8 * 4);
    float*          ed2  = (float*)alloc((size_t)N_NODES * 4);
    int*            deg  = (int*)alloc((size_t)N_NODES * 4);
    int*            colPad = (int*)alloc((size_t)N_NODES * MAXDEG * 4);
    int2*           ebuf = (int2*)alloc((size_t)NBIN * BINCAP * 8);
    int*            gctr = (int*)alloc((size_t)NBIN * 4);

    hipMemsetAsync(gctr, 0, NBIN * 4, stream);

    k_prep<<<NBLK_WT, 256, 0, stream>>>(W1, Bh, Bl);
    // fused: binning (196 blocks) hidden under the GEMM (782 blocks)
    k_gemm1b<<<NBLK_E + NBLK_G1, 256, 0, stream>>>(X, Bh, Bl, a1s, a1d, es1, wh1, ed1,
                                                   src, dst, ebuf, gctr);
    k_csr<<<NBIN, 256, 0, stream>>>(ebuf, gctr, deg, colPad);
    k_agg1g2<<<(N_NODES + 31) / 32, 256, 0, stream>>>(es1, wh1, ed1, deg, colPad,
                                                      W2, a2s, a2d, es2, wh2, ed2);
    k_agg2<<<(N_NODES * 8 + 255) / 256, 256, 0, stream>>>(es2, wh2, ed2, deg, colPad, out);
}

// Round 6
// 257.753 us; speedup vs baseline: 1.3397x; 1.0460x over previous
//
#include <hip/hip_runtime.h>
#include <math.h>

#define N_NODES 50000
#define N_EDGES 800000
#define F_IN    512
#define H1      8
#define F_HID   8
#define C1      64      // H1*F_HID
#define NLAB    64
#define SLOPE   0.2f
#define MAXDEG  64      // multinomial(800K,50K): mean 16, max ~35; 64 is safe

#define NBIN    98      // coarse node bins of 512 nodes (98*512 = 50176)
#define BINCAP  9216    // per-bin edge capacity: mean 8163, sigma ~90 -> +11 sigma
#define NBLK_WT  128    // 64*512/256 W1-split blocks
#define NBLK_E   196    // ceil(800000/4096) edge-binning blocks
#define NBLK_G1  782    // (50000+63)/64 gemm1 row-blocks

typedef __attribute__((ext_vector_type(8))) short short8;
typedef __attribute__((ext_vector_type(4))) float f32x4;

__device__ __forceinline__ float bf_lo(unsigned u) { return __uint_as_float(u << 16); }
__device__ __forceinline__ float bf_hi(unsigned u) { return __uint_as_float(u & 0xFFFF0000u); }
__device__ __forceinline__ unsigned short f2bf(float x) {
    unsigned bits = __float_as_uint(x);
    return (unsigned short)((bits + 0x7FFF + ((bits >> 16) & 1)) >> 16);   // RNE
}

// ---------------- prep: W1 bf16 split only (tiny) ----------------
__global__ void k_prep(const float* __restrict__ W1, unsigned short* __restrict__ Bh,
                       unsigned short* __restrict__ Bl) {
    int i = blockIdx.x * 256 + threadIdx.x;   // 0..32767
    int c = i >> 9, f = i & 511;
    float v = W1[(c >> 3) * (F_IN * F_HID) + f * F_HID + (c & 7)];
    unsigned bits = __float_as_uint(v);
    float r = v - __uint_as_float(bits & 0xFFFF0000u);
    Bh[i] = (unsigned short)(bits >> 16);
    Bl[i] = (unsigned short)(__float_as_uint(r) >> 16);
}

// -------- GEMM1 + es/ed pack, FUSED with edge BINNING (unchanged from R5) --------
__launch_bounds__(256, 4)
__global__ void k_gemm1b(const float* __restrict__ X, const unsigned short* __restrict__ Bh,
                         const unsigned short* __restrict__ Bl, const float* __restrict__ a_s,
                         const float* __restrict__ a_d, float* __restrict__ es1,
                         unsigned short* __restrict__ wh1, float* __restrict__ ed,
                         const int* __restrict__ src, const int* __restrict__ dst,
                         int2* __restrict__ ebuf, int* __restrict__ gctr) {
    __shared__ unsigned short sBh[64][136];
    __shared__ unsigned short sBl[64][136];

    const int b = blockIdx.x;
    const int t = threadIdx.x;
    if (b < NBLK_E) {              // ---- edge binning path ----
        int* hist = (int*)&sBh[0][0];
        int* cur  = hist + 128;
        if (t < NBIN) hist[t] = 0;
        __syncthreads();
        int4 dv[4], sv[4];
        const int e0 = b * 4096 + t * 4;
        #pragma unroll
        for (int i = 0; i < 4; i++) {
            int e = e0 + i * 1024;
            if (e < N_EDGES) {
                dv[i] = *(const int4*)(dst + e);
                sv[i] = *(const int4*)(src + e);
                atomicAdd(&hist[dv[i].x >> 9], 1);
                atomicAdd(&hist[dv[i].y >> 9], 1);
                atomicAdd(&hist[dv[i].z >> 9], 1);
                atomicAdd(&hist[dv[i].w >> 9], 1);
            }
        }
        __syncthreads();
        if (t < NBIN) cur[t] = atomicAdd(&gctr[t], hist[t]);
        __syncthreads();
        #pragma unroll
        for (int i = 0; i < 4; i++) {
            int e = e0 + i * 1024;
            if (e < N_EDGES) {
                int d, s, sl;
                d = dv[i].x; s = sv[i].x; sl = atomicAdd(&cur[d >> 9], 1);
                ebuf[(size_t)(d >> 9) * BINCAP + min(sl, BINCAP - 1)] = make_int2(d, s);
                d = dv[i].y; s = sv[i].y; sl = atomicAdd(&cur[d >> 9], 1);
                ebuf[(size_t)(d >> 9) * BINCAP + min(sl, BINCAP - 1)] = make_int2(d, s);
                d = dv[i].z; s = sv[i].z; sl = atomicAdd(&cur[d >> 9], 1);
                ebuf[(size_t)(d >> 9) * BINCAP + min(sl, BINCAP - 1)] = make_int2(d, s);
                d = dv[i].w; s = sv[i].w; sl = atomicAdd(&cur[d >> 9], 1);
                ebuf[(size_t)(d >> 9) * BINCAP + min(sl, BINCAP - 1)] = make_int2(d, s);
            }
        }
        return;
    }

    const int lane = t & 63, w = t >> 6;
    const int r0 = (b - NBLK_E) * 64 + w * 16;
    const int m = lane & 15, quad = lane >> 4;
    int row = r0 + m; if (row >= N_NODES) row = N_NODES - 1;
    const float* xrow = X + (size_t)row * F_IN + quad * 8;

    const int sc = t >> 2;
    const int sp = t & 3;

    f32x4 acc[4] = {};
    float4 pxa[4], pxb[4];
    #pragma unroll
    for (int i = 0; i < 4; i++) {
        pxa[i] = *(const float4*)(xrow + i * 32);
        pxb[i] = *(const float4*)(xrow + i * 32 + 4);
    }

    for (int chunk = 0; chunk < 4; chunk++) {
        const int k0 = chunk * 128;
        if (chunk) __syncthreads();
        #pragma unroll
        for (int i = 0; i < 4; i++) {
            *(short8*)(&sBh[sc][sp * 32 + i * 8]) =
                *(const short8*)(Bh + sc * F_IN + k0 + sp * 32 + i * 8);
            *(short8*)(&sBl[sc][sp * 32 + i * 8]) =
                *(const short8*)(Bl + sc * F_IN + k0 + sp * 32 + i * 8);
        }
        __syncthreads();
        #pragma unroll
        for (int i = 0; i < 4; i++) {
            float xs[8] = {pxa[i].x, pxa[i].y, pxa[i].z, pxa[i].w,
                           pxb[i].x, pxb[i].y, pxb[i].z, pxb[i].w};
            if (chunk < 3) {
                const int ktn = k0 + 128 + i * 32;
                pxa[i] = *(const float4*)(xrow + ktn);
                pxb[i] = *(const float4*)(xrow + ktn + 4);
            }
            short8 ah, al;
            #pragma unroll
            for (int j = 0; j < 8; j++) {
                unsigned bits = __float_as_uint(xs[j]);
                float rr = xs[j] - __uint_as_float(bits & 0xFFFF0000u);
                ah[j] = (short)(bits >> 16);
                al[j] = (short)(__float_as_uint(rr) >> 16);
            }
            #pragma unroll
            for (int s = 0; s < 4; s++) {
                short8 bh = *(const short8*)(&sBh[s * 16 + m][i * 32 + quad * 8]);
                short8 bl = *(const short8*)(&sBl[s * 16 + m][i * 32 + quad * 8]);
                acc[s] = __builtin_amdgcn_mfma_f32_16x16x32_bf16(al, bh, acc[s], 0, 0, 0);
                acc[s] = __builtin_amdgcn_mfma_f32_16x16x32_bf16(ah, bl, acc[s], 0, 0, 0);
                acc[s] = __builtin_amdgcn_mfma_f32_16x16x32_bf16(ah, bh, acc[s], 0, 0, 0);
            }
        }
    }
    __syncthreads();
    unsigned short* sWh = &sBh[0][0] + w * 1024;
    #pragma unroll
    for (int s = 0; s < 4; s++)
        #pragma unroll
        for (int reg = 0; reg < 4; reg++)
            sWh[(quad * 4 + reg) * 64 + s * 16 + m] = f2bf(acc[s][reg]);
    __syncthreads();
    const int rr = lane & 15, p = lane >> 4;
    const int n = r0 + rr;
    if (n >= N_NODES) return;
    float es2v[2], edv[2];
    #pragma unroll
    for (int hh = 0; hh < 2; hh++) {
        int h = 2 * p + hh;
        float s = 0.f, dsum = 0.f;
        #pragma unroll
        for (int j = 0; j < 8; j++) {
            float v = __uint_as_float((unsigned)sWh[rr * 64 + h * 8 + j] << 16);
            s += v * a_s[h * 8 + j];
            dsum += v * a_d[h * 8 + j];
        }
        es2v[hh] = s; edv[hh] = dsum;
    }
    *(float2*)(es1 + n * 8 + 2 * p) = make_float2(es2v[0], es2v[1]);
    *(short8*)(wh1 + (size_t)n * 64 + p * 16)     = *(const short8*)(sWh + rr * 64 + p * 16);
    *(short8*)(wh1 + (size_t)n * 64 + p * 16 + 8) = *(const short8*)(sWh + rr * 64 + p * 16 + 8);
    *(float2*)(ed + n * 8 + 2 * p) = make_float2(edv[0], edv[1]);
}

// ---------------- per-bin CSR build (LDS-only slot atomics) ----------------
__global__ void k_csr(const int2* __restrict__ ebuf, const int* __restrict__ gctr,
                      int* __restrict__ deg, int* __restrict__ colPad) {
    __shared__ int cnt[512];
    const int b = blockIdx.x, t = threadIdx.x;
    const int lo = b << 9;
    const int cnum = min(gctr[b], BINCAP);
    for (int i = t; i < 512; i += 256) cnt[i] = 0;
    __syncthreads();
    const int2* eb2 = ebuf + (size_t)b * BINCAP;
    for (int i = t; i < cnum; i += 256) {
        int2 e = eb2[i];
        int sl = atomicAdd(&cnt[e.x - lo], 1);       // LDS atomic
        colPad[(e.x << 6) | min(sl, MAXDEG - 1)] = e.y;
    }
    __syncthreads();
    for (int i = t; i < 512; i += 256) {
        int n = lo + i;
        if (n < N_NODES) deg[n] = min(cnt[i], MAXDEG);
    }
}

// -------- FUSED layer-1 aggregation + GEMM2: SHFL-FREE inner loop --------
// colPad rows for the block's 32 nodes staged in LDS (padded [32][68] to
// spread banks). Inner loop is a plain dynamic-bound loop: 1 broadcast
// ds_read for the slot id + 2 independent global gathers per edge; no
// cross-lane ops, no 64-slot unrolled walk. #pragma unroll 4 => 8 global
// loads in flight per lane.
__launch_bounds__(256)
__global__ void k_agg1g2(const float* __restrict__ es1, const unsigned short* __restrict__ wh1,
                         const float* __restrict__ ed,
                         const int* __restrict__ deg, const int* __restrict__ colPad,
                         const float* __restrict__ W2, const float* __restrict__ a2s,
                         const float* __restrict__ a2d,
                         float* __restrict__ es2, unsigned short* __restrict__ wh2,
                         float* __restrict__ ed2) {
    __shared__ float Ws[64 * 64];    // 16KB
    __shared__ float hs[32][64];     // 8KB
    __shared__ int scol[32][68];     // 8.5KB (pad 68: groups hit distinct banks)
    const int t = threadIdx.x;
    #pragma unroll
    for (int i = 0; i < 4; i++) {
        int flat = i * 256 + t;
        *(float4*)(Ws + flat * 4) = *(const float4*)(W2 + flat * 4);
    }
    const int n0 = blockIdx.x * 32;
    // stage colPad rows: 32 nodes * 16 int4 = 512 int4
    for (int i = t; i < 512; i += 256) {
        size_t gi = (size_t)n0 * 16 + i;
        int4 v = (gi < (size_t)N_NODES * 16) ? ((const int4*)colPad)[gi]
                                             : make_int4(0, 0, 0, 0);
        *(int4*)&scol[i >> 4][(i & 15) * 4] = v;
    }
    __syncthreads();

    const int nl = t >> 3, q = t & 7;
    const int n = n0 + nl;
    float o[8] = {};
    if (n < N_NODES) {
        const int d = deg[n];
        const float edq = ed[n * 8 + q];
        float den = 0.f;
        float acc[8] = {};
        #pragma unroll 4
        for (int e = 0; e < d; ++e) {
            int sv = scol[nl][e];
            float x = es1[sv * 8 + q] + edq;
            uint4 u = *(const uint4*)(wh1 + (size_t)sv * 64 + q * 8);
            x = x > 0.f ? x : SLOPE * x;
            float wg = __expf(x);
            den += wg;
            acc[0] += wg * bf_lo(u.x); acc[1] += wg * bf_hi(u.x);
            acc[2] += wg * bf_lo(u.y); acc[3] += wg * bf_hi(u.y);
            acc[4] += wg * bf_lo(u.z); acc[5] += wg * bf_hi(u.z);
            acc[6] += wg * bf_lo(u.w); acc[7] += wg * bf_hi(u.w);
        }
        float inv = 1.f / (den + 1e-10f);
        #pragma unroll
        for (int j = 0; j < 8; j++) {
            float v = acc[j] * inv;
            o[j] = v > 0.f ? v : expm1f(v);   // fused ELU
        }
    }
    float4* hp = (float4*)(&hs[nl][q * 8]);
    hp[0] = make_float4(o[0], o[1], o[2], o[3]);
    hp[1] = make_float4(o[4], o[5], o[6], o[7]);
    __syncthreads();

    // ---- GEMM2 phase: wave wv handles 8 nodes, lane = output class ----
    const int wv = t >> 6, lane = t & 63;
    float as = a2s[lane], ad = a2d[lane];
    #pragma unroll
    for (int j = 0; j < 8; j++) {
        int nn = n0 + wv * 8 + j;
        if (nn >= N_NODES) break;
        float acc = 0.f;
        #pragma unroll
        for (int k = 0; k < 64; k++) acc += hs[wv * 8 + j][k] * Ws[k * 64 + lane];
        wh2[(size_t)nn * 64 + lane] = f2bf(acc);
        float s = acc * as;
        float dd = acc * ad;
        #pragma unroll
        for (int off = 1; off < 64; off <<= 1) {
            s += __shfl_xor(s, off);
            dd += __shfl_xor(dd, off);
        }
        if (lane == 0) { es2[nn] = s; ed2[nn] = dd; }
    }
}

// ------- layer-2 aggregation: SHFL-FREE inner loop + fused final softmax -------
__launch_bounds__(256)
__global__ void k_agg2(const float* __restrict__ es2, const unsigned short* __restrict__ wh2,
                       const float* __restrict__ ed2,
                       const int* __restrict__ deg, const int* __restrict__ colPad,
                       float* __restrict__ out) {
    __shared__ int scol[32][68];
    const int t = threadIdx.x;
    const int n0 = blockIdx.x * 32;
    for (int i = t; i < 512; i += 256) {
        size_t gi = (size_t)n0 * 16 + i;
        int4 v = (gi < (size_t)N_NODES * 16) ? ((const int4*)colPad)[gi]
                                             : make_int4(0, 0, 0, 0);
        *(int4*)&scol[i >> 4][(i & 15) * 4] = v;
    }
    __syncthreads();

    const int nl = t >> 3, q = t & 7;
    const int n = n0 + nl;
    if (n >= N_NODES) return;
    const int d = deg[n];
    const float edn = ed2[n];

    float den = 0.f;
    float acc[8] = {};
    #pragma unroll 4
    for (int e = 0; e < d; ++e) {
        int sv = scol[nl][e];
        float x = es2[sv] + edn;
        uint4 u = *(const uint4*)(wh2 + (size_t)sv * 64 + q * 8);
        x = x > 0.f ? x : SLOPE * x;
        float wg = __expf(x);
        den += wg;
        acc[0] += wg * bf_lo(u.x); acc[1] += wg * bf_hi(u.x);
        acc[2] += wg * bf_lo(u.y); acc[3] += wg * bf_hi(u.y);
        acc[4] += wg * bf_lo(u.z); acc[5] += wg * bf_hi(u.z);
        acc[6] += wg * bf_lo(u.w); acc[7] += wg * bf_hi(u.w);
    }
    float inv = 1.f / (den + 1e-10f);
    float o[8];
    #pragma unroll
    for (int j = 0; j < 8; j++) o[j] = acc[j] * inv;
    // softmax over 64 classes spread across the 8-lane group (xor 1,2,4 stays in-group)
    float mx = o[0];
    #pragma unroll
    for (int j = 1; j < 8; j++) mx = fmaxf(mx, o[j]);
    mx = fmaxf(mx, __shfl_xor(mx, 1));
    mx = fmaxf(mx, __shfl_xor(mx, 2));
    mx = fmaxf(mx, __shfl_xor(mx, 4));
    float e8[8], sm = 0.f;
    #pragma unroll
    for (int j = 0; j < 8; j++) { e8[j] = __expf(o[j] - mx); sm += e8[j]; }
    sm += __shfl_xor(sm, 1);
    sm += __shfl_xor(sm, 2);
    sm += __shfl_xor(sm, 4);
    float inv2 = 1.f / sm;
    float4* op = (float4*)(out + (size_t)n * 64 + q * 8);
    op[0] = make_float4(e8[0] * inv2, e8[1] * inv2, e8[2] * inv2, e8[3] * inv2);
    op[1] = make_float4(e8[4] * inv2, e8[5] * inv2, e8[6] * inv2, e8[7] * inv2);
}

// ---------------- launcher (5 dispatches + tiny memset) ----------------
extern "C" void kernel_launch(void* const* d_in, const int* in_sizes, int n_in,
                              void* d_out, int out_size, void* d_ws, size_t ws_size,
                              hipStream_t stream) {
    const float* X   = (const float*)d_in[0];
    const float* W1  = (const float*)d_in[1];
    const float* a1s = (const float*)d_in[2];
    const float* a1d = (const float*)d_in[3];
    const float* W2  = (const float*)d_in[4];
    const float* a2s = (const float*)d_in[5];
    const float* a2d = (const float*)d_in[6];
    const int*   src = (const int*)d_in[7];
    const int*   dst = (const int*)d_in[8];
    float* out = (float*)d_out;

    char* w = (char*)d_ws;
    size_t off = 0;
    auto alloc = [&](size_t bytes) {
        void* p = w + off;
        off += (bytes + 255) & ~(size_t)255;
        return p;
    };
    unsigned short* Bh   = (unsigned short*)alloc((size_t)C1 * F_IN * 2);
    unsigned short* Bl   = (unsigned short*)alloc((size_t)C1 * F_IN * 2);
    float*          es1  = (float*)alloc((size_t)N_NODES * 8 * 4);
    unsigned short* wh1  = (unsigned short*)alloc((size_t)N_NODES * 64 * 2);
    float*          es2  = (float*)alloc((size_t)N_NODES * 4);
    unsigned short* wh2  = (unsigned short*)alloc((size_t)N_NODES * 64 * 2);
    float*          ed1  = (float*)alloc((size_t)N_NODES * 8 * 4);
    float*          ed2  = (float*)alloc((size_t)N_NODES * 4);
    int*            deg  = (int*)alloc((size_t)N_NODES * 4);
    int*            colPad = (int*)alloc((size_t)N_NODES * MAXDEG * 4);
    int2*           ebuf = (int2*)alloc((size_t)NBIN * BINCAP * 8);
    int*            gctr = (int*)alloc((size_t)NBIN * 4);

    hipMemsetAsync(gctr, 0, NBIN * 4, stream);

    k_prep<<<NBLK_WT, 256, 0, stream>>>(W1, Bh, Bl);
    // fused: binning (196 blocks) hidden under the GEMM (782 blocks)
    k_gemm1b<<<NBLK_E + NBLK_G1, 256, 0, stream>>>(X, Bh, Bl, a1s, a1d, es1, wh1, ed1,
                                                   src, dst, ebuf, gctr);
    k_csr<<<NBIN, 256, 0, stream>>>(ebuf, gctr, deg, colPad);
    k_agg1g2<<<(N_NODES + 31) / 32, 256, 0, stream>>>(es1, wh1, ed1, deg, colPad,
                                                      W2, a2s, a2d, es2, wh2, ed2);
    k_agg2<<<(N_NODES + 31) / 32, 256, 0, stream>>>(es2, wh2, ed2, deg, colPad, out);
}